// Round 1
// baseline (581.850 us; speedup 1.0000x reference)
//
#include <hip/hip_runtime.h>
#include <stdint.h>

#define VROWS 131072
#define DIM   1024
#define TTHRESH 0.33f
#define TEPS    1e-10f
#define CAP   16384

// ws layout (bytes):
//   hist    : int[1025]           @ 0
//   gcount  : int                 @ 4352
//   t_state : int8[1024]          @ 4608
//   matches : uint32[VROWS]       @ 8192
//   keys    : uint64[CAP]         @ 8192 + 4*VROWS = 532480
#define HIST_OFF   0
#define GCOUNT_OFF 4352
#define TSTATE_OFF 4608
#define MATCH_OFF  8192
#define KEYS_OFF   (8192 + 4 * VROWS)

__device__ __forceinline__ int tern(float n) {
    return n > TTHRESH ? 1 : (n < -TTHRESH ? -1 : 0);
}

// ---------------- K0: zero scratch, ternarize query ----------------
__global__ __launch_bounds__(256) void k0_prep(const float* __restrict__ q,
                                               signed char* __restrict__ ts,
                                               int* __restrict__ hist,
                                               int* __restrict__ gcount) {
    __shared__ float red[256];
    int t = threadIdx.x;
    for (int i = t; i < 1025; i += 256) hist[i] = 0;
    if (t == 0) *gcount = 0;
    float4 v = ((const float4*)q)[t];  // 256*4 = 1024 elements
    float m = fmaxf(fmaxf(fabsf(v.x), fabsf(v.y)), fmaxf(fabsf(v.z), fabsf(v.w)));
    red[t] = m;
    __syncthreads();
    for (int s = 128; s > 0; s >>= 1) {
        if (t < s) red[t] = fmaxf(red[t], red[t + s]);
        __syncthreads();
    }
    float denom = red[0] + TEPS;
    char4 c;
    c.x = (signed char)tern(v.x / denom);
    c.y = (signed char)tern(v.y / denom);
    c.z = (signed char)tern(v.z / denom);
    c.w = (signed char)tern(v.w / denom);
    ((char4*)ts)[t] = c;
}

// ---------------- K1: per-row ternary match count ----------------
__device__ __forceinline__ int cmp4(float4 a, int w, float denom) {
    int c = 0;
    c += (tern(a.x / denom) == (int)(signed char)(w & 0xFF));
    c += (tern(a.y / denom) == (int)(signed char)((w >> 8) & 0xFF));
    c += (tern(a.z / denom) == (int)(signed char)((w >> 16) & 0xFF));
    c += (tern(a.w / denom) == (int)(signed char)((w >> 24) & 0xFF));
    return c;
}

__global__ __launch_bounds__(256) void k1_coarse(const float* __restrict__ W,
                                                 const int* __restrict__ ts_words,
                                                 uint32_t* __restrict__ matches,
                                                 int* __restrict__ hist) {
    __shared__ int tl[256];
    int t = threadIdx.x;
    tl[t] = ts_words[t];
    __syncthreads();
    int wave = t >> 6, lane = t & 63;
    int row = (blockIdx.x << 2) + wave;           // 4 rows per block, 1 per wave
    const float4* Wr = (const float4*)(W + (size_t)row * DIM);
    float4 a0 = Wr[lane];
    float4 a1 = Wr[64 + lane];
    float4 a2 = Wr[128 + lane];
    float4 a3 = Wr[192 + lane];
    float m = fmaxf(fmaxf(fabsf(a0.x), fabsf(a0.y)), fmaxf(fabsf(a0.z), fabsf(a0.w)));
    m = fmaxf(m, fmaxf(fmaxf(fabsf(a1.x), fabsf(a1.y)), fmaxf(fabsf(a1.z), fabsf(a1.w))));
    m = fmaxf(m, fmaxf(fmaxf(fabsf(a2.x), fabsf(a2.y)), fmaxf(fabsf(a2.z), fabsf(a2.w))));
    m = fmaxf(m, fmaxf(fmaxf(fabsf(a3.x), fabsf(a3.y)), fmaxf(fabsf(a3.z), fabsf(a3.w))));
    for (int s = 1; s < 64; s <<= 1) m = fmaxf(m, __shfl_xor(m, s));
    float denom = m + TEPS;
    int cnt = cmp4(a0, tl[lane], denom)
            + cmp4(a1, tl[64 + lane], denom)
            + cmp4(a2, tl[128 + lane], denom)
            + cmp4(a3, tl[192 + lane], denom);
    for (int s = 1; s < 64; s <<= 1) cnt += __shfl_xor(cnt, s);
    if (lane == 0) {
        matches[row] = (uint32_t)cnt;
        atomicAdd(&hist[cnt], 1);
    }
}

// ---------------- K2: threshold, gather, select top-k3, refine, top-K ----------------
__global__ __launch_bounds__(1024) void k2_refine(const float* __restrict__ W,
                                                  const float* __restrict__ q,
                                                  const int* __restrict__ topk,
                                                  const uint32_t* __restrict__ matches,
                                                  const int* __restrict__ hist,
                                                  unsigned long long* __restrict__ keys,
                                                  int* __restrict__ gcount,
                                                  float* __restrict__ out) {
    __shared__ __align__(16) float qs[DIM];
    __shared__ float redf[1024];
    __shared__ unsigned long long redk[1024];
    __shared__ int redi[1024];
    __shared__ int sel[192];
    __shared__ float refined[192];
    __shared__ int sT, sK, sK3;
    __shared__ float sQn;
    int t = threadIdx.x;
    if (t < 256) ((float4*)qs)[t] = ((const float4*)q)[t];
    __syncthreads();

    // query norm (1024 threads == DIM)
    float qv = qs[t];
    redf[t] = qv * qv;
    __syncthreads();
    for (int s = 512; s > 0; s >>= 1) {
        if (t < s) redf[t] += redf[t + s];
        __syncthreads();
    }
    if (t == 0) {
        sQn = sqrtf(redf[0]) + 1e-12f;
        int K = *topk;
        if (K < 1) K = 1;
        if (K > 64) K = 64;
        int k3 = 3 * K;
        if (k3 > VROWS) k3 = VROWS;
        sK = K;
        sK3 = k3;
        int c = 0, T = 0;
        for (int m2 = 1024; m2 >= 0; --m2) {
            c += hist[m2];
            if (c >= k3) { T = m2; break; }
        }
        sT = T;
    }
    __syncthreads();
    int T = sT, K = sK, k3 = sK3;

    // gather candidates with matches >= T
    for (int v = t; v < VROWS; v += 1024) {
        uint32_t mm = matches[v];
        if ((int)mm >= T) {
            int pos = atomicAdd(gcount, 1);
            if (pos < CAP)
                keys[pos] = ((unsigned long long)mm << 32) | (unsigned int)(~v);
        }
    }
    __syncthreads();
    int G = *gcount;
    if (G > CAP) G = CAP;

    // select top-k3 keys: (matches desc, index asc) == jax.lax.top_k tie order
    for (int i = 0; i < k3; ++i) {
        unsigned long long best = 0ull;
        int bpos = -1;
        for (int j = t; j < G; j += 1024) {
            unsigned long long kk = keys[j];
            if (kk > best) { best = kk; bpos = j; }
        }
        redk[t] = best;
        redi[t] = bpos;
        __syncthreads();
        for (int s = 512; s > 0; s >>= 1) {
            if (t < s) {
                if (redk[t + s] > redk[t]) { redk[t] = redk[t + s]; redi[t] = redi[t + s]; }
            }
            __syncthreads();
        }
        if (t == 0) {
            sel[i] = (int)(~(unsigned int)redk[0]);
            keys[redi[0]] = 0ull;   // remove from further consideration
        }
        __syncthreads();
    }

    // refine: cosine similarity for each of the k3 candidates (1 wave per candidate, round-robin)
    int wave = t >> 6, lane = t & 63;
    float qn = sQn;
    for (int i = wave; i < k3; i += 16) {
        int row = sel[i];
        const float4* Wr = (const float4*)(W + (size_t)row * DIM);
        float dot = 0.f, ss = 0.f;
        for (int j2 = 0; j2 < 4; ++j2) {
            float4 a = Wr[j2 * 64 + lane];
            float4 b = ((const float4*)qs)[j2 * 64 + lane];
            dot += a.x * b.x + a.y * b.y + a.z * b.z + a.w * b.w;
            ss  += a.x * a.x + a.y * a.y + a.z * a.z + a.w * a.w;
        }
        for (int s = 1; s < 64; s <<= 1) {
            dot += __shfl_xor(dot, s);
            ss  += __shfl_xor(ss, s);
        }
        if (lane == 0) refined[i] = dot / ((sqrtf(ss) + 1e-12f) * qn);
    }
    __syncthreads();

    // final top-K of refined (value desc, earliest-candidate tie-break), write out
    if (t == 0) {
        for (int i = 0; i < K; ++i) {
            float best = -1e30f;
            int bj = 0;
            for (int j = 0; j < k3; ++j) {
                if (refined[j] > best) { best = refined[j]; bj = j; }
            }
            out[i] = best;
            out[K + i] = (float)sel[bj];
            refined[bj] = -2e30f;
        }
    }
}

extern "C" void kernel_launch(void* const* d_in, const int* in_sizes, int n_in,
                              void* d_out, int out_size, void* d_ws, size_t ws_size,
                              hipStream_t stream) {
    const float* q = (const float*)d_in[0];
    const float* W = (const float*)d_in[1];
    const int* topk = (const int*)d_in[2];
    float* out = (float*)d_out;
    char* ws = (char*)d_ws;

    int* hist = (int*)(ws + HIST_OFF);
    int* gcount = (int*)(ws + GCOUNT_OFF);
    signed char* ts = (signed char*)(ws + TSTATE_OFF);
    uint32_t* matches = (uint32_t*)(ws + MATCH_OFF);
    unsigned long long* keys = (unsigned long long*)(ws + KEYS_OFF);

    k0_prep<<<1, 256, 0, stream>>>(q, ts, hist, gcount);
    k1_coarse<<<VROWS / 4, 256, 0, stream>>>(W, (const int*)ts, matches, hist);
    k2_refine<<<1, 1024, 0, stream>>>(W, q, topk, matches, hist, keys, gcount, out);
}

// Round 2
// 238.324 us; speedup vs baseline: 2.4414x; 2.4414x over previous
//
#include <hip/hip_runtime.h>
#include <stdint.h>

#define VROWS 131072
#define DIM   1024
#define TTHRESH 0.33f
#define TEPS    1e-10f
#define CAP   16384
#define NB    32          // histogram blocks

// ws layout (bytes):
//   partials : int[NB*1025]   @ 0          (131200 B)  -- reused as keys[] later
//   keys     : uint64[CAP]    @ 0          (131072 B)  -- overlaps partials (consumed first)
//   gcount   : int            @ 131200
//   t_state  : int8[1024]     @ 131264
//   matches  : uint32[VROWS]  @ 132288     (524288 B)
#define PART_OFF   0
#define KEYS_OFF   0
#define GCOUNT_OFF 131200
#define TSTATE_OFF 131264
#define MATCH_OFF  132288

__device__ __forceinline__ int tern(float n) {
    return n > TTHRESH ? 1 : (n < -TTHRESH ? -1 : 0);
}

// ---------------- K0: zero gcount, ternarize query ----------------
__global__ __launch_bounds__(256) void k0_prep(const float* __restrict__ q,
                                               signed char* __restrict__ ts,
                                               int* __restrict__ gcount) {
    __shared__ float red[256];
    int t = threadIdx.x;
    if (t == 0) *gcount = 0;
    float4 v = ((const float4*)q)[t];  // 256*4 = 1024 elements
    float m = fmaxf(fmaxf(fabsf(v.x), fabsf(v.y)), fmaxf(fabsf(v.z), fabsf(v.w)));
    red[t] = m;
    __syncthreads();
    for (int s = 128; s > 0; s >>= 1) {
        if (t < s) red[t] = fmaxf(red[t], red[t + s]);
        __syncthreads();
    }
    float denom = red[0] + TEPS;
    char4 c;
    c.x = (signed char)tern(v.x / denom);
    c.y = (signed char)tern(v.y / denom);
    c.z = (signed char)tern(v.z / denom);
    c.w = (signed char)tern(v.w / denom);
    ((char4*)ts)[t] = c;
}

// ---------------- K1: per-row ternary match count (no atomics) ----------------
__device__ __forceinline__ int cmp4(float4 a, int w, float denom) {
    int c = 0;
    c += (tern(a.x / denom) == (int)(signed char)(w & 0xFF));
    c += (tern(a.y / denom) == (int)(signed char)((w >> 8) & 0xFF));
    c += (tern(a.z / denom) == (int)(signed char)((w >> 16) & 0xFF));
    c += (tern(a.w / denom) == (int)(signed char)((w >> 24) & 0xFF));
    return c;
}

__device__ __forceinline__ float max4abs(float4 a) {
    return fmaxf(fmaxf(fabsf(a.x), fabsf(a.y)), fmaxf(fabsf(a.z), fabsf(a.w)));
}

__global__ __launch_bounds__(256) void k1_coarse(const float* __restrict__ W,
                                                 const int* __restrict__ ts_words,
                                                 uint32_t* __restrict__ matches) {
    __shared__ int tl[256];
    int t = threadIdx.x;
    tl[t] = ts_words[t];
    __syncthreads();
    int wave = t >> 6, lane = t & 63;
    int r0 = (blockIdx.x << 3) + wave;       // 8 rows per block, 2 per wave
    int r1 = r0 + 4;
    const float4* W0 = (const float4*)(W + (size_t)r0 * DIM);
    const float4* W1 = (const float4*)(W + (size_t)r1 * DIM);
    float4 a0 = W0[lane],       b0 = W1[lane];
    float4 a1 = W0[64 + lane],  b1 = W1[64 + lane];
    float4 a2 = W0[128 + lane], b2 = W1[128 + lane];
    float4 a3 = W0[192 + lane], b3 = W1[192 + lane];
    float ma = fmaxf(fmaxf(max4abs(a0), max4abs(a1)), fmaxf(max4abs(a2), max4abs(a3)));
    float mb = fmaxf(fmaxf(max4abs(b0), max4abs(b1)), fmaxf(max4abs(b2), max4abs(b3)));
    for (int s = 1; s < 64; s <<= 1) {
        ma = fmaxf(ma, __shfl_xor(ma, s));
        mb = fmaxf(mb, __shfl_xor(mb, s));
    }
    float da = ma + TEPS, db = mb + TEPS;
    int w0 = tl[lane], w1 = tl[64 + lane], w2 = tl[128 + lane], w3 = tl[192 + lane];
    int ca = cmp4(a0, w0, da) + cmp4(a1, w1, da) + cmp4(a2, w2, da) + cmp4(a3, w3, da);
    int cb = cmp4(b0, w0, db) + cmp4(b1, w1, db) + cmp4(b2, w2, db) + cmp4(b3, w3, db);
    for (int s = 1; s < 64; s <<= 1) {
        ca += __shfl_xor(ca, s);
        cb += __shfl_xor(cb, s);
    }
    if (lane == 0) {
        matches[r0] = (uint32_t)ca;
        matches[r1] = (uint32_t)cb;
    }
}

// ---------------- K1b: per-block LDS histogram -> partials (no global atomics) ----------------
__global__ __launch_bounds__(1024) void k1b_hist(const uint32_t* __restrict__ matches,
                                                 int* __restrict__ partials) {
    __shared__ int h[1025];
    int t = threadIdx.x;
    if (t == 0) h[1024] = 0;
    h[t] = 0;
    __syncthreads();
    int gid = blockIdx.x * 1024 + t;           // NB*1024 threads, 1 int4 (4 rows) each
    int4 m4 = ((const int4*)matches)[gid];
    atomicAdd(&h[m4.x], 1);
    atomicAdd(&h[m4.y], 1);
    atomicAdd(&h[m4.z], 1);
    atomicAdd(&h[m4.w], 1);
    __syncthreads();
    int* dst = partials + blockIdx.x * 1025;
    dst[t] = h[t];
    if (t == 0) dst[1024] = h[1024];
}

// ---------------- K2: merge hist, threshold, gather, top-k3, refine, top-K ----------------
__global__ __launch_bounds__(1024) void k2_refine(const float* __restrict__ W,
                                                  const float* __restrict__ q,
                                                  const int* __restrict__ topk,
                                                  const uint32_t* __restrict__ matches,
                                                  const int* __restrict__ partials,
                                                  unsigned long long* __restrict__ keys,
                                                  int* __restrict__ gcount,
                                                  float* __restrict__ out) {
    __shared__ __align__(16) float qs[DIM];
    __shared__ int S[2048];                 // suffix-scan workspace
    __shared__ float redf[1024];
    __shared__ unsigned long long rk[16];
    __shared__ int ri[16];
    __shared__ int sel[192];
    __shared__ float refined[192];
    __shared__ int sT, sK, sK3;
    __shared__ float sQn;
    int t = threadIdx.x;

    // load q + query norm
    if (t < 256) ((float4*)qs)[t] = ((const float4*)q)[t];
    __syncthreads();
    float qv = qs[t];
    redf[t] = qv * qv;
    __syncthreads();
    for (int s = 512; s > 0; s >>= 1) {
        if (t < s) redf[t] += redf[t + s];
        __syncthreads();
    }
    if (t == 0) {
        sQn = sqrtf(redf[0]) + 1e-12f;
        int K = *topk;
        if (K < 1) K = 1;
        if (K > 64) K = 64;
        sK = K;
        int k3 = 3 * K;
        if (k3 > VROWS) k3 = VROWS;
        sK3 = k3;
    }

    // merge NB partial histograms (parallel, coalesced per k)
    int hb = 0, hb1 = 0;
    for (int k = 0; k < NB; ++k) {
        hb += partials[k * 1025 + t];
        if (t == 0) hb1 += partials[k * 1025 + 1024];
    }
    S[t] = hb;
    S[1024 + t] = (t == 0) ? hb1 : 0;
    __syncthreads();

    // parallel suffix sum over S[0..2047] (pads are zero)
    for (int s = 1; s < 2048; s <<= 1) {
        int a = S[t] + ((t + s < 2048) ? S[t + s] : 0);
        int b = S[1024 + t] + ((1024 + t + s < 2048) ? S[1024 + t + s] : 0);
        __syncthreads();
        S[t] = a;
        S[1024 + t] = b;
        __syncthreads();
    }
    int k3 = sK3;
    // T = largest m with suffix[m] >= k3 (suffix is non-increasing)
    if (S[t] >= k3 && S[t + 1] < k3) sT = t;
    if (t == 0 && S[1024] >= k3) sT = 1024;   // S[1025]==0 < k3
    __syncthreads();
    int T = sT, K = sK;

    // gather candidates with matches >= T (unordered; total-order key fixes determinism)
    for (int v = t; v < VROWS; v += 1024) {
        uint32_t mm = matches[v];
        if ((int)mm >= T) {
            int pos = atomicAdd(gcount, 1);
            if (pos < CAP)
                keys[pos] = ((unsigned long long)mm << 32) | (unsigned int)(~v);
        }
    }
    __syncthreads();
    int G = *gcount;
    if (G > CAP) G = CAP;

    // select top-k3 keys: (matches desc, index asc) == jax.lax.top_k tie order
    int wave = t >> 6, lane = t & 63;
    for (int i = 0; i < k3; ++i) {
        unsigned long long best = 0ull;
        int bpos = -1;
        for (int j = t; j < G; j += 1024) {
            unsigned long long kk = keys[j];
            if (kk > best) { best = kk; bpos = j; }
        }
        for (int s = 1; s < 64; s <<= 1) {
            unsigned long long ob = __shfl_xor(best, s);
            int op = __shfl_xor(bpos, s);
            if (ob > best) { best = ob; bpos = op; }
        }
        if (lane == 0) { rk[wave] = best; ri[wave] = bpos; }
        __syncthreads();
        if (t == 0) {
            unsigned long long bb = rk[0];
            int bp = ri[0];
            for (int w2 = 1; w2 < 16; ++w2)
                if (rk[w2] > bb) { bb = rk[w2]; bp = ri[w2]; }
            sel[i] = (int)(~(unsigned int)bb);
            keys[bp] = 0ull;
        }
        __syncthreads();
    }

    // refine: cosine similarity (1 wave per candidate, round-robin)
    float qn = sQn;
    for (int i = wave; i < k3; i += 16) {
        int row = sel[i];
        const float4* Wr = (const float4*)(W + (size_t)row * DIM);
        float dot = 0.f, ss = 0.f;
        for (int j2 = 0; j2 < 4; ++j2) {
            float4 a = Wr[j2 * 64 + lane];
            float4 b = ((const float4*)qs)[j2 * 64 + lane];
            dot += a.x * b.x + a.y * b.y + a.z * b.z + a.w * b.w;
            ss  += a.x * a.x + a.y * a.y + a.z * a.z + a.w * a.w;
        }
        for (int s = 1; s < 64; s <<= 1) {
            dot += __shfl_xor(dot, s);
            ss  += __shfl_xor(ss, s);
        }
        if (lane == 0) refined[i] = dot / ((sqrtf(ss) + 1e-12f) * qn);
    }
    __syncthreads();

    // final top-K (value desc, earliest-candidate tie-break), write out
    if (t == 0) {
        for (int i = 0; i < K; ++i) {
            float best = -1e30f;
            int bj = 0;
            for (int j = 0; j < k3; ++j) {
                if (refined[j] > best) { best = refined[j]; bj = j; }
            }
            out[i] = best;
            out[K + i] = (float)sel[bj];
            refined[bj] = -2e30f;
        }
    }
}

extern "C" void kernel_launch(void* const* d_in, const int* in_sizes, int n_in,
                              void* d_out, int out_size, void* d_ws, size_t ws_size,
                              hipStream_t stream) {
    const float* q = (const float*)d_in[0];
    const float* W = (const float*)d_in[1];
    const int* topk = (const int*)d_in[2];
    float* out = (float*)d_out;
    char* ws = (char*)d_ws;

    int* partials = (int*)(ws + PART_OFF);
    unsigned long long* keys = (unsigned long long*)(ws + KEYS_OFF);
    int* gcount = (int*)(ws + GCOUNT_OFF);
    signed char* ts = (signed char*)(ws + TSTATE_OFF);
    uint32_t* matches = (uint32_t*)(ws + MATCH_OFF);

    k0_prep<<<1, 256, 0, stream>>>(q, ts, gcount);
    k1_coarse<<<VROWS / 8, 256, 0, stream>>>(W, (const int*)ts, matches);
    k1b_hist<<<NB, 1024, 0, stream>>>(matches, partials);
    k2_refine<<<1, 1024, 0, stream>>>(W, q, topk, matches, partials, keys, gcount, out);
}

// Round 3
// 166.984 us; speedup vs baseline: 3.4845x; 1.4272x over previous
//
#include <hip/hip_runtime.h>
#include <stdint.h>

#define VROWS 131072
#define DIM   1024
#define TTHRESH 0.33f
#define TEPS    1e-10f
#define NBLK  256                      // kB blocks
#define ROWS_PER_BLK (VROWS / NBLK)    // 512
#define CAPL  4096                     // kC LDS gather capacity

// Exact rounding boundary: RN(x/d) > 0.33f  <=>  x >= MBOUND*d (d>0, exact in double).
// 0.33f has odd mantissa LSB; succ(0.33f) even => tie rounds up => inclusive >=.
#define MBOUND ((double)TTHRESH + 0x1p-26)

// ws layout (bytes):
//   ts       : int8[1024]       @ 0
//   matches  : int32[VROWS]     @ 1024
//   partials : int[NBLK*1025]   @ 1024 + 4*VROWS
#define TS_OFF    0
#define MATCH_OFF 1024
#define PART_OFF  (1024 + 4 * VROWS)

__device__ __forceinline__ int tern(float n) {
    return n > TTHRESH ? 1 : (n < -TTHRESH ? -1 : 0);
}

// ---------------- kA: ternarize query (exact reference arithmetic, tiny) ----------------
__global__ __launch_bounds__(256) void kA_prep(const float* __restrict__ q,
                                               signed char* __restrict__ ts) {
    __shared__ float red[256];
    int t = threadIdx.x;
    float4 v = ((const float4*)q)[t];
    float m = fmaxf(fmaxf(fabsf(v.x), fabsf(v.y)), fmaxf(fabsf(v.z), fabsf(v.w)));
    red[t] = m;
    __syncthreads();
    for (int s = 128; s > 0; s >>= 1) {
        if (t < s) red[t] = fmaxf(red[t], red[t + s]);
        __syncthreads();
    }
    float denom = red[0] + TEPS;
    char4 c;
    c.x = (signed char)tern(v.x / denom);
    c.y = (signed char)tern(v.y / denom);
    c.z = (signed char)tern(v.z / denom);
    c.w = (signed char)tern(v.w / denom);
    ((char4*)ts)[t] = c;
}

// ---------------- kB: stream table, match-count per row, per-block histogram ----------------
__device__ __forceinline__ int matchElem(float x, int tq, double md) {
    double xd = (double)x;
    bool nz = fabs(xd) >= md;                 // |x|/d crosses threshold (exact)
    int tt = nz ? ((x > 0.f) ? 1 : -1) : 0;
    return tt == tq ? 1 : 0;
}

__device__ __forceinline__ int match4(float4 a, int w, double md) {
    return matchElem(a.x, (int)(signed char)(w & 0xFF), md)
         + matchElem(a.y, (int)(signed char)((w >> 8) & 0xFF), md)
         + matchElem(a.z, (int)(signed char)((w >> 16) & 0xFF), md)
         + matchElem(a.w, (int)(signed char)((w >> 24) & 0xFF), md);
}

__device__ __forceinline__ float max4abs(float4 a) {
    return fmaxf(fmaxf(fabsf(a.x), fabsf(a.y)), fmaxf(fabsf(a.z), fabsf(a.w)));
}

__global__ __launch_bounds__(1024) void kB_coarse(const float* __restrict__ W,
                                                  const int* __restrict__ ts_words,
                                                  int* __restrict__ matches,
                                                  int* __restrict__ partials) {
    __shared__ int tl[256];
    __shared__ int h[1025];
    int t = threadIdx.x;
    if (t < 256) tl[t] = ts_words[t];
    h[t] = 0;
    if (t == 0) h[1024] = 0;
    __syncthreads();
    int wave = t >> 6, lane = t & 63;
    int w0 = tl[lane], w1 = tl[64 + lane], w2 = tl[128 + lane], w3 = tl[192 + lane];
    int base = blockIdx.x * ROWS_PER_BLK;
#pragma unroll 2
    for (int it = 0; it < 16; ++it) {
        int r0 = base + it * 32 + wave * 2;     // 16 waves x 2 rows = 32 rows / iter
        int r1 = r0 + 1;
        const float4* W0 = (const float4*)(W + (size_t)r0 * DIM);
        const float4* W1 = (const float4*)(W + (size_t)r1 * DIM);
        float4 a0 = W0[lane],       b0 = W1[lane];
        float4 a1 = W0[64 + lane],  b1 = W1[64 + lane];
        float4 a2 = W0[128 + lane], b2 = W1[128 + lane];
        float4 a3 = W0[192 + lane], b3 = W1[192 + lane];
        float ma = fmaxf(fmaxf(max4abs(a0), max4abs(a1)), fmaxf(max4abs(a2), max4abs(a3)));
        float mb = fmaxf(fmaxf(max4abs(b0), max4abs(b1)), fmaxf(max4abs(b2), max4abs(b3)));
        for (int s = 1; s < 64; s <<= 1) {
            ma = fmaxf(ma, __shfl_xor(ma, s));
            mb = fmaxf(mb, __shfl_xor(mb, s));
        }
        float da = ma + TEPS, db = mb + TEPS;   // f32 add exactly as reference
        double mda = MBOUND * (double)da;       // exact 49-bit product
        double mdb = MBOUND * (double)db;
        int ca = match4(a0, w0, mda) + match4(a1, w1, mda) + match4(a2, w2, mda) + match4(a3, w3, mda);
        int cb = match4(b0, w0, mdb) + match4(b1, w1, mdb) + match4(b2, w2, mdb) + match4(b3, w3, mdb);
        for (int s = 1; s < 64; s <<= 1) {
            ca += __shfl_xor(ca, s);
            cb += __shfl_xor(cb, s);
        }
        if (lane == 0) {
            matches[r0] = ca;
            matches[r1] = cb;
            atomicAdd(&h[ca], 1);
            atomicAdd(&h[cb], 1);
        }
    }
    __syncthreads();
    int* dst = partials + blockIdx.x * 1025;
    dst[t] = h[t];
    if (t == 0) dst[1024] = h[1024];
}

// ---------------- kC: merge hist, threshold, gather, rank-select, refine, output ----------------
__global__ __launch_bounds__(1024) void kC_refine(const float* __restrict__ W,
                                                  const float* __restrict__ q,
                                                  const int* __restrict__ topk,
                                                  const int* __restrict__ matches,
                                                  const int* __restrict__ partials,
                                                  float* __restrict__ out) {
    __shared__ __align__(16) float qs[DIM];
    __shared__ int S[2048];
    __shared__ float redf[1024];
    __shared__ unsigned long long keys[CAPL];
    __shared__ int sel[192];
    __shared__ float refined[192];
    __shared__ int gcnt;
    __shared__ int sT, sK, sK3;
    __shared__ float sQn;
    int t = threadIdx.x;

    if (t < 256) ((float4*)qs)[t] = ((const float4*)q)[t];
    if (t == 0) gcnt = 0;
    __syncthreads();

    // query norm
    float qv = qs[t];
    redf[t] = qv * qv;
    __syncthreads();
    for (int s = 512; s > 0; s >>= 1) {
        if (t < s) redf[t] += redf[t + s];
        __syncthreads();
    }
    if (t == 0) {
        sQn = sqrtf(redf[0]) + 1e-12f;
        int K = *topk;
        if (K < 1) K = 1;
        if (K > 64) K = 64;
        sK = K;
        int k3 = 3 * K;
        if (k3 > VROWS) k3 = VROWS;
        sK3 = k3;
    }

    // merge NBLK partial histograms (coalesced across t)
    int hb = 0, hb1 = 0;
    for (int k = 0; k < NBLK; ++k) {
        hb += partials[k * 1025 + t];
        if (t == 0) hb1 += partials[k * 1025 + 1024];
    }
    S[t] = hb;
    S[1024 + t] = (t == 0) ? hb1 : 0;
    __syncthreads();

    // parallel suffix sum over S[0..2047]
    for (int s = 1; s < 2048; s <<= 1) {
        int a = S[t] + ((t + s < 2048) ? S[t + s] : 0);
        int b = S[1024 + t] + ((1024 + t + s < 2048) ? S[1024 + t + s] : 0);
        __syncthreads();
        S[t] = a;
        S[1024 + t] = b;
        __syncthreads();
    }
    int k3 = sK3;
    if (S[t] >= k3 && S[t + 1] < k3) sT = t;
    if (t == 0 && S[1024] >= k3) sT = 1024;
    __syncthreads();
    int T = sT, K = sK;

    // gather candidates (matches >= T); order arbitrary, rank-count fixes determinism
    for (int i = 0; i < 32; ++i) {
        int j = i * 1024 + t;                       // int4 index
        int4 m4 = ((const int4*)matches)[j];
        int rbase = j * 4;
        if (m4.x >= T) { int p = atomicAdd(&gcnt, 1); if (p < CAPL) keys[p] = ((unsigned long long)m4.x << 32) | (unsigned int)(~(rbase)); }
        if (m4.y >= T) { int p = atomicAdd(&gcnt, 1); if (p < CAPL) keys[p] = ((unsigned long long)m4.y << 32) | (unsigned int)(~(rbase + 1)); }
        if (m4.z >= T) { int p = atomicAdd(&gcnt, 1); if (p < CAPL) keys[p] = ((unsigned long long)m4.z << 32) | (unsigned int)(~(rbase + 2)); }
        if (m4.w >= T) { int p = atomicAdd(&gcnt, 1); if (p < CAPL) keys[p] = ((unsigned long long)m4.w << 32) | (unsigned int)(~(rbase + 3)); }
    }
    __syncthreads();
    int G = gcnt;

    // pathological-overflow fallback (never taken for this data; correctness insurance)
    if (G > CAPL) {
        if (t == 0) {
            int n = 0;
            for (int v = 0; v < VROWS && n < k3; ++v)
                if (matches[v] > T) keys[n++] = ((unsigned long long)matches[v] << 32) | (unsigned int)(~v);
            for (int v = 0; v < VROWS && n < k3; ++v)
                if (matches[v] == T) keys[n++] = ((unsigned long long)matches[v] << 32) | (unsigned int)(~v);
            gcnt = n;
        }
        __syncthreads();
        G = gcnt;
    }

    // rank-count selection of top-k3 (matches desc, index asc)
    for (int i = t; i < G; i += 1024) {
        unsigned long long ki = keys[i];
        int rank = 0;
        for (int j = 0; j < G; ++j) rank += (keys[j] > ki) ? 1 : 0;
        if (rank < k3) sel[rank] = (int)(~(unsigned int)ki);
    }
    __syncthreads();

    // refine: cosine similarity, 1 wave per candidate round-robin
    int wave = t >> 6, lane = t & 63;
    float qn = sQn;
    for (int i = wave; i < k3; i += 16) {
        int row = sel[i];
        const float4* Wr = (const float4*)(W + (size_t)row * DIM);
        float dot = 0.f, ss = 0.f;
        for (int j2 = 0; j2 < 4; ++j2) {
            float4 a = Wr[j2 * 64 + lane];
            float4 b = ((const float4*)qs)[j2 * 64 + lane];
            dot += a.x * b.x + a.y * b.y + a.z * b.z + a.w * b.w;
            ss  += a.x * a.x + a.y * a.y + a.z * a.z + a.w * a.w;
        }
        for (int s = 1; s < 64; s <<= 1) {
            dot += __shfl_xor(dot, s);
            ss  += __shfl_xor(ss, s);
        }
        if (lane == 0) refined[i] = dot / ((sqrtf(ss) + 1e-12f) * qn);
    }
    __syncthreads();

    // final top-K by rank-count (value desc, candidate-position asc)
    if (t < k3) {
        float rv = refined[t];
        int rank = 0;
        for (int j = 0; j < k3; ++j)
            rank += ((refined[j] > rv) || (refined[j] == rv && j < t)) ? 1 : 0;
        if (rank < K) {
            out[rank] = rv;
            out[K + rank] = (float)sel[t];
        }
    }
}

extern "C" void kernel_launch(void* const* d_in, const int* in_sizes, int n_in,
                              void* d_out, int out_size, void* d_ws, size_t ws_size,
                              hipStream_t stream) {
    const float* q = (const float*)d_in[0];
    const float* W = (const float*)d_in[1];
    const int* topk = (const int*)d_in[2];
    float* out = (float*)d_out;
    char* ws = (char*)d_ws;

    signed char* ts = (signed char*)(ws + TS_OFF);
    int* matches = (int*)(ws + MATCH_OFF);
    int* partials = (int*)(ws + PART_OFF);

    kA_prep<<<1, 256, 0, stream>>>(q, ts);
    kB_coarse<<<NBLK, 1024, 0, stream>>>(W, (const int*)ts, matches, partials);
    kC_refine<<<1, 1024, 0, stream>>>(W, q, topk, matches, partials, out);
}

// Round 4
// 148.961 us; speedup vs baseline: 3.9061x; 1.1210x over previous
//
#include <hip/hip_runtime.h>
#include <stdint.h>

#define VROWS 131072
#define DIM   1024
#define TTHRESH 0.33f
#define TEPS    1e-10f
#define KB_BLOCKS 2048                 // 64 rows/block, 4 waves, 16 rows/wave
#define NHB   32                       // histogram blocks
#define CAPL  4096                     // kC LDS gather capacity

// Exact rounding boundary: RN(x/d) > 0.33f  <=>  x >= MBOUND*d (d>0, exact in double).
// 0.33f has odd mantissa LSB; succ(0.33f) even => tie rounds up => inclusive >=.
#define MBOUND ((double)TTHRESH + 0x1p-26)

// ws layout (bytes):
//   ts       : int8[1024]       @ 0
//   matches  : int32[VROWS]     @ 1024
//   partials : int[NHB*1025]    @ 1024 + 4*VROWS
#define TS_OFF    0
#define MATCH_OFF 1024
#define PART_OFF  (1024 + 4 * VROWS)

__device__ __forceinline__ int tern(float n) {
    return n > TTHRESH ? 1 : (n < -TTHRESH ? -1 : 0);
}

__device__ __forceinline__ float max4abs(float4 a) {
    return fmaxf(fmaxf(fabsf(a.x), fabsf(a.y)), fmaxf(fabsf(a.z), fabsf(a.w)));
}

// ---------------- kA: ternarize query (exact reference arithmetic, tiny) ----------------
__global__ __launch_bounds__(256) void kA_prep(const float* __restrict__ q,
                                               signed char* __restrict__ ts) {
    __shared__ float red[256];
    int t = threadIdx.x;
    float4 v = ((const float4*)q)[t];
    red[t] = max4abs(v);
    __syncthreads();
    for (int s = 128; s > 0; s >>= 1) {
        if (t < s) red[t] = fmaxf(red[t], red[t + s]);
        __syncthreads();
    }
    float denom = red[0] + TEPS;
    char4 c;
    c.x = (signed char)tern(v.x / denom);
    c.y = (signed char)tern(v.y / denom);
    c.z = (signed char)tern(v.z / denom);
    c.w = (signed char)tern(v.w / denom);
    ((char4*)ts)[t] = c;
}

// ---------------- kB: stream table, per-row ternary match count ----------------
__device__ __forceinline__ int classify1(float x, float tq, float r) {
    float tv = (fabsf(x) >= r) ? __builtin_copysignf(1.f, x) : 0.f;
    return (tv == tq) ? 1 : 0;
}

__device__ __forceinline__ int class4(float4 a, const float* tq, float r) {
    return classify1(a.x, tq[0], r) + classify1(a.y, tq[1], r)
         + classify1(a.z, tq[2], r) + classify1(a.w, tq[3], r);
}

__global__ __launch_bounds__(256) void kB_coarse(const float* __restrict__ W,
                                                 const int* __restrict__ ts_words,
                                                 int* __restrict__ matches) {
    __shared__ int tl[256];
    int t = threadIdx.x;
    tl[t] = ts_words[t];
    __syncthreads();
    int wave = t >> 6, lane = t & 63;
    float tqf[16];
#pragma unroll
    for (int j = 0; j < 4; ++j) {
        int w = tl[j * 64 + lane];
        tqf[j * 4 + 0] = (float)(signed char)(w & 0xFF);
        tqf[j * 4 + 1] = (float)(signed char)((w >> 8) & 0xFF);
        tqf[j * 4 + 2] = (float)(signed char)((w >> 16) & 0xFF);
        tqf[j * 4 + 3] = (float)(signed char)((w >> 24) & 0xFF);
    }
    int row0 = blockIdx.x * 64 + wave * 16;
    const float4* p = (const float4*)(W + (size_t)row0 * DIM);
    float4 c0 = p[lane], c1 = p[64 + lane], c2 = p[128 + lane], c3 = p[192 + lane];
#pragma unroll 1
    for (int i = 0; i < 16; ++i) {
        // prefetch next row (wraps to row0 on last iter; harmless, stays in range)
        const float4* pn = (const float4*)(W + (size_t)(row0 + ((i + 1) & 15)) * DIM);
        float4 n0 = pn[lane], n1 = pn[64 + lane], n2 = pn[128 + lane], n3 = pn[192 + lane];
        // row max |.|
        float m = fmaxf(fmaxf(max4abs(c0), max4abs(c1)), fmaxf(max4abs(c2), max4abs(c3)));
        for (int s = 1; s < 64; s <<= 1) m = fmaxf(m, __shfl_xor(m, s));
        float d = m + TEPS;                       // f32, as reference
        double md = MBOUND * (double)d;           // exact 49-bit product
        float r = (float)md;                      // smallest f32 >= md:
        if (!((double)r >= md)) r = __int_as_float(__float_as_int(r) + 1);
        int cnt = class4(c0, &tqf[0], r) + class4(c1, &tqf[4], r)
                + class4(c2, &tqf[8], r) + class4(c3, &tqf[12], r);
        for (int s = 1; s < 64; s <<= 1) cnt += __shfl_xor(cnt, s);
        if (lane == 0) matches[row0 + i] = cnt;
        c0 = n0; c1 = n1; c2 = n2; c3 = n3;
    }
}

// ---------------- kHist: per-block LDS histogram -> partials ----------------
__global__ __launch_bounds__(1024) void kHist(const int* __restrict__ matches,
                                              int* __restrict__ partials) {
    __shared__ int h[1025];
    int t = threadIdx.x;
    if (t == 0) h[1024] = 0;
    h[t] = 0;
    __syncthreads();
    int gid = blockIdx.x * 1024 + t;            // NHB*1024 threads, 1 int4 (4 rows) each
    int4 m4 = ((const int4*)matches)[gid];
    atomicAdd(&h[m4.x], 1);
    atomicAdd(&h[m4.y], 1);
    atomicAdd(&h[m4.z], 1);
    atomicAdd(&h[m4.w], 1);
    __syncthreads();
    int* dst = partials + blockIdx.x * 1025;
    dst[t] = h[t];
    if (t == 0) dst[1024] = h[1024];
}

// ---------------- kC: merge hist, threshold, gather, rank-select, refine, output ----------------
__global__ __launch_bounds__(1024) void kC_refine(const float* __restrict__ W,
                                                  const float* __restrict__ q,
                                                  const int* __restrict__ topk,
                                                  const int* __restrict__ matches,
                                                  const int* __restrict__ partials,
                                                  float* __restrict__ out) {
    __shared__ __align__(16) float qs[DIM];
    __shared__ int S[2048];
    __shared__ float redf[1024];
    __shared__ unsigned long long keys[CAPL];
    __shared__ int sel[192];
    __shared__ float refined[192];
    __shared__ int gcnt;
    __shared__ int sT, sK, sK3;
    __shared__ float sQn;
    int t = threadIdx.x;

    if (t < 256) ((float4*)qs)[t] = ((const float4*)q)[t];
    if (t == 0) gcnt = 0;
    __syncthreads();

    // query norm
    float qv = qs[t];
    redf[t] = qv * qv;
    __syncthreads();
    for (int s = 512; s > 0; s >>= 1) {
        if (t < s) redf[t] += redf[t + s];
        __syncthreads();
    }
    if (t == 0) {
        sQn = sqrtf(redf[0]) + 1e-12f;
        int K = *topk;
        if (K < 1) K = 1;
        if (K > 64) K = 64;
        sK = K;
        int k3 = 3 * K;
        if (k3 > VROWS) k3 = VROWS;
        sK3 = k3;
    }

    // merge NHB partial histograms (coalesced across t)
    int hb = 0, hb1 = 0;
    for (int k = 0; k < NHB; ++k) {
        hb += partials[k * 1025 + t];
        if (t == 0) hb1 += partials[k * 1025 + 1024];
    }
    S[t] = hb;
    S[1024 + t] = (t == 0) ? hb1 : 0;
    __syncthreads();

    // parallel suffix sum over S[0..2047]
    for (int s = 1; s < 2048; s <<= 1) {
        int a = S[t] + ((t + s < 2048) ? S[t + s] : 0);
        int b = S[1024 + t] + ((1024 + t + s < 2048) ? S[1024 + t + s] : 0);
        __syncthreads();
        S[t] = a;
        S[1024 + t] = b;
        __syncthreads();
    }
    int k3 = sK3;
    if (S[t] >= k3 && S[t + 1] < k3) sT = t;
    if (t == 0 && S[1024] >= k3) sT = 1024;
    __syncthreads();
    int T = sT, K = sK;

    // gather candidates (matches >= T); order arbitrary, rank-count fixes determinism
    for (int i = 0; i < 32; ++i) {
        int j = i * 1024 + t;                       // int4 index
        int4 m4 = ((const int4*)matches)[j];
        int rbase = j * 4;
        if (m4.x >= T) { int p = atomicAdd(&gcnt, 1); if (p < CAPL) keys[p] = ((unsigned long long)m4.x << 32) | (unsigned int)(~(rbase)); }
        if (m4.y >= T) { int p = atomicAdd(&gcnt, 1); if (p < CAPL) keys[p] = ((unsigned long long)m4.y << 32) | (unsigned int)(~(rbase + 1)); }
        if (m4.z >= T) { int p = atomicAdd(&gcnt, 1); if (p < CAPL) keys[p] = ((unsigned long long)m4.z << 32) | (unsigned int)(~(rbase + 2)); }
        if (m4.w >= T) { int p = atomicAdd(&gcnt, 1); if (p < CAPL) keys[p] = ((unsigned long long)m4.w << 32) | (unsigned int)(~(rbase + 3)); }
    }
    __syncthreads();
    int G = gcnt;

    // pathological-overflow fallback (never taken for this data; correctness insurance)
    if (G > CAPL) {
        if (t == 0) {
            int n = 0;
            for (int v = 0; v < VROWS && n < k3; ++v)
                if (matches[v] > T) keys[n++] = ((unsigned long long)matches[v] << 32) | (unsigned int)(~v);
            for (int v = 0; v < VROWS && n < k3; ++v)
                if (matches[v] == T) keys[n++] = ((unsigned long long)matches[v] << 32) | (unsigned int)(~v);
            gcnt = n;
        }
        __syncthreads();
        G = gcnt;
    }

    // rank-count selection of top-k3 (matches desc, index asc)
    for (int i = t; i < G; i += 1024) {
        unsigned long long ki = keys[i];
        int rank = 0;
        for (int j = 0; j < G; ++j) rank += (keys[j] > ki) ? 1 : 0;
        if (rank < k3) sel[rank] = (int)(~(unsigned int)ki);
    }
    __syncthreads();

    // refine: cosine similarity, 1 wave per candidate round-robin
    int wave = t >> 6, lane = t & 63;
    float qn = sQn;
    for (int i = wave; i < k3; i += 16) {
        int row = sel[i];
        const float4* Wr = (const float4*)(W + (size_t)row * DIM);
        float dot = 0.f, ss = 0.f;
        for (int j2 = 0; j2 < 4; ++j2) {
            float4 a = Wr[j2 * 64 + lane];
            float4 b = ((const float4*)qs)[j2 * 64 + lane];
            dot += a.x * b.x + a.y * b.y + a.z * b.z + a.w * b.w;
            ss  += a.x * a.x + a.y * a.y + a.z * a.z + a.w * a.w;
        }
        for (int s = 1; s < 64; s <<= 1) {
            dot += __shfl_xor(dot, s);
            ss  += __shfl_xor(ss, s);
        }
        if (lane == 0) refined[i] = dot / ((sqrtf(ss) + 1e-12f) * qn);
    }
    __syncthreads();

    // final top-K by rank-count (value desc, candidate-position asc)
    if (t < k3) {
        float rv = refined[t];
        int rank = 0;
        for (int j = 0; j < k3; ++j)
            rank += ((refined[j] > rv) || (refined[j] == rv && j < t)) ? 1 : 0;
        if (rank < K) {
            out[rank] = rv;
            out[K + rank] = (float)sel[t];
        }
    }
}

extern "C" void kernel_launch(void* const* d_in, const int* in_sizes, int n_in,
                              void* d_out, int out_size, void* d_ws, size_t ws_size,
                              hipStream_t stream) {
    const float* q = (const float*)d_in[0];
    const float* W = (const float*)d_in[1];
    const int* topk = (const int*)d_in[2];
    float* out = (float*)d_out;
    char* ws = (char*)d_ws;

    signed char* ts = (signed char*)(ws + TS_OFF);
    int* matches = (int*)(ws + MATCH_OFF);
    int* partials = (int*)(ws + PART_OFF);

    kA_prep<<<1, 256, 0, stream>>>(q, ts);
    kB_coarse<<<KB_BLOCKS, 256, 0, stream>>>(W, (const int*)ts, matches);
    kHist<<<NHB, 1024, 0, stream>>>(matches, partials);
    kC_refine<<<1, 1024, 0, stream>>>(W, q, topk, matches, partials, out);
}

// Round 5
// 147.458 us; speedup vs baseline: 3.9459x; 1.0102x over previous
//
#include <hip/hip_runtime.h>
#include <stdint.h>

#define VROWS 131072
#define DIM   1024
#define TTHRESH 0.33f
#define TEPS    1e-10f
#define KB_BLOCKS 2048                 // 64 rows/block, 4 waves, 16 rows/wave
#define NHB   32                       // histogram blocks
#define CAPL  4096                     // kC LDS gather capacity

// Exact rounding boundary: RN(x/d) > 0.33f  <=>  x >= MBOUND*d (d>0, exact in double).
// 0.33f has odd mantissa LSB; succ(0.33f) even => tie rounds up => inclusive >=.
#define MBOUND ((double)TTHRESH + 0x1p-26)

// ws layout (bytes):
//   ts       : int8[1024]       @ 0
//   matches  : int32[VROWS]     @ 1024
//   partials : int[NHB*1025]    @ 1024 + 4*VROWS
#define TS_OFF    0
#define MATCH_OFF 1024
#define PART_OFF  (1024 + 4 * VROWS)

__device__ __forceinline__ int tern(float n) {
    return n > TTHRESH ? 1 : (n < -TTHRESH ? -1 : 0);
}

__device__ __forceinline__ float max4abs(float4 a) {
    return fmaxf(fmaxf(fabsf(a.x), fabsf(a.y)), fmaxf(fabsf(a.z), fabsf(a.w)));
}

// ---------------- kA: ternarize query (exact reference arithmetic, tiny) ----------------
__global__ __launch_bounds__(256) void kA_prep(const float* __restrict__ q,
                                               signed char* __restrict__ ts) {
    __shared__ float red[256];
    int t = threadIdx.x;
    float4 v = ((const float4*)q)[t];
    red[t] = max4abs(v);
    __syncthreads();
    for (int s = 128; s > 0; s >>= 1) {
        if (t < s) red[t] = fmaxf(red[t], red[t + s]);
        __syncthreads();
    }
    float denom = red[0] + TEPS;
    char4 c;
    c.x = (signed char)tern(v.x / denom);
    c.y = (signed char)tern(v.y / denom);
    c.z = (signed char)tern(v.z / denom);
    c.w = (signed char)tern(v.w / denom);
    ((char4*)ts)[t] = c;
}

// ---------------- kB: stream table, ballot-based per-row ternary match count ----------------
// Per 64-element slot: two wave compares -> masks combined on the scalar pipe.
__device__ __forceinline__ int slotcnt(float x, int sxj, unsigned long long M0j, float r) {
    float xs = __int_as_float(__float_as_int(x) ^ sxj);     // sign-flip where tq == -1
    unsigned long long b1 = __ballot(xs >= r);              // |tq|==1 match (masked)
    unsigned long long b0 = __ballot(fabsf(x) < r);         // tq==0 match (masked)
    return (int)__popcll((b1 & ~M0j) | (b0 & M0j));
}

__global__ __launch_bounds__(256) void kB_coarse(const float* __restrict__ W,
                                                 const int* __restrict__ ts_words,
                                                 int* __restrict__ matches) {
    __shared__ int tl[256];
    int t = threadIdx.x;
    tl[t] = ts_words[t];
    __syncthreads();
    int wave = t >> 6, lane = t & 63;
    int sx[16];
    unsigned long long M0[16];
#pragma unroll
    for (int j = 0; j < 4; ++j) {
        int w = tl[j * 64 + lane];
        int q0 = (int)(signed char)(w & 0xFF);
        int q1 = (int)(signed char)((w >> 8) & 0xFF);
        int q2 = (int)(signed char)((w >> 16) & 0xFF);
        int q3 = (int)(signed char)((w >> 24) & 0xFF);
        sx[j * 4 + 0] = (q0 < 0) ? (int)0x80000000 : 0;
        sx[j * 4 + 1] = (q1 < 0) ? (int)0x80000000 : 0;
        sx[j * 4 + 2] = (q2 < 0) ? (int)0x80000000 : 0;
        sx[j * 4 + 3] = (q3 < 0) ? (int)0x80000000 : 0;
        M0[j * 4 + 0] = __ballot(q0 == 0);
        M0[j * 4 + 1] = __ballot(q1 == 0);
        M0[j * 4 + 2] = __ballot(q2 == 0);
        M0[j * 4 + 3] = __ballot(q3 == 0);
    }
    int row0 = blockIdx.x * 64 + wave * 16;
    const float4* p = (const float4*)(W + (size_t)row0 * DIM);
    float4 c0 = p[lane], c1 = p[64 + lane], c2 = p[128 + lane], c3 = p[192 + lane];
#pragma unroll 1
    for (int i = 0; i < 16; ++i) {
        // prefetch next row (wraps to row0 on last iter; harmless, stays in range)
        const float4* pn = (const float4*)(W + (size_t)(row0 + ((i + 1) & 15)) * DIM);
        float4 n0 = pn[lane], n1 = pn[64 + lane], n2 = pn[128 + lane], n3 = pn[192 + lane];
        // row max |.| (single cross-lane chain per row)
        float m = fmaxf(fmaxf(max4abs(c0), max4abs(c1)), fmaxf(max4abs(c2), max4abs(c3)));
        for (int s = 1; s < 64; s <<= 1) m = fmaxf(m, __shfl_xor(m, s));
        float d = m + TEPS;                       // f32, as reference
        double md = MBOUND * (double)d;           // exact 49-bit product
        float r = (float)md;                      // smallest f32 >= md:
        if (!((double)r >= md)) r = __int_as_float(__float_as_int(r) + 1);
        int cnt = 0;
        cnt += slotcnt(c0.x, sx[0],  M0[0],  r);
        cnt += slotcnt(c0.y, sx[1],  M0[1],  r);
        cnt += slotcnt(c0.z, sx[2],  M0[2],  r);
        cnt += slotcnt(c0.w, sx[3],  M0[3],  r);
        cnt += slotcnt(c1.x, sx[4],  M0[4],  r);
        cnt += slotcnt(c1.y, sx[5],  M0[5],  r);
        cnt += slotcnt(c1.z, sx[6],  M0[6],  r);
        cnt += slotcnt(c1.w, sx[7],  M0[7],  r);
        cnt += slotcnt(c2.x, sx[8],  M0[8],  r);
        cnt += slotcnt(c2.y, sx[9],  M0[9],  r);
        cnt += slotcnt(c2.z, sx[10], M0[10], r);
        cnt += slotcnt(c2.w, sx[11], M0[11], r);
        cnt += slotcnt(c3.x, sx[12], M0[12], r);
        cnt += slotcnt(c3.y, sx[13], M0[13], r);
        cnt += slotcnt(c3.z, sx[14], M0[14], r);
        cnt += slotcnt(c3.w, sx[15], M0[15], r);
        if (lane == 0) matches[row0 + i] = cnt;
        c0 = n0; c1 = n1; c2 = n2; c3 = n3;
    }
}

// ---------------- kHist: per-block LDS histogram -> partials ----------------
__global__ __launch_bounds__(1024) void kHist(const int* __restrict__ matches,
                                              int* __restrict__ partials) {
    __shared__ int h[1025];
    int t = threadIdx.x;
    if (t == 0) h[1024] = 0;
    h[t] = 0;
    __syncthreads();
    int gid = blockIdx.x * 1024 + t;            // NHB*1024 threads, 1 int4 (4 rows) each
    int4 m4 = ((const int4*)matches)[gid];
    atomicAdd(&h[m4.x], 1);
    atomicAdd(&h[m4.y], 1);
    atomicAdd(&h[m4.z], 1);
    atomicAdd(&h[m4.w], 1);
    __syncthreads();
    int* dst = partials + blockIdx.x * 1025;
    dst[t] = h[t];
    if (t == 0) dst[1024] = h[1024];
}

// ---------------- kC: merge hist, threshold, gather, rank-select, refine, output ----------------
__global__ __launch_bounds__(1024) void kC_refine(const float* __restrict__ W,
                                                  const float* __restrict__ q,
                                                  const int* __restrict__ topk,
                                                  const int* __restrict__ matches,
                                                  const int* __restrict__ partials,
                                                  float* __restrict__ out) {
    __shared__ __align__(16) float qs[DIM];
    __shared__ int S[2048];
    __shared__ float redf[1024];
    __shared__ unsigned long long keys[CAPL];
    __shared__ int sel[192];
    __shared__ float refined[192];
    __shared__ int gcnt;
    __shared__ int sT, sK, sK3;
    __shared__ float sQn;
    int t = threadIdx.x;

    if (t < 256) ((float4*)qs)[t] = ((const float4*)q)[t];
    if (t == 0) gcnt = 0;
    __syncthreads();

    // query norm
    float qv = qs[t];
    redf[t] = qv * qv;
    __syncthreads();
    for (int s = 512; s > 0; s >>= 1) {
        if (t < s) redf[t] += redf[t + s];
        __syncthreads();
    }
    if (t == 0) {
        sQn = sqrtf(redf[0]) + 1e-12f;
        int K = *topk;
        if (K < 1) K = 1;
        if (K > 64) K = 64;
        sK = K;
        int k3 = 3 * K;
        if (k3 > VROWS) k3 = VROWS;
        sK3 = k3;
    }

    // merge NHB partial histograms (coalesced across t)
    int hb = 0, hb1 = 0;
    for (int k = 0; k < NHB; ++k) {
        hb += partials[k * 1025 + t];
        if (t == 0) hb1 += partials[k * 1025 + 1024];
    }
    S[t] = hb;
    S[1024 + t] = (t == 0) ? hb1 : 0;
    __syncthreads();

    // parallel suffix sum over S[0..2047]
    for (int s = 1; s < 2048; s <<= 1) {
        int a = S[t] + ((t + s < 2048) ? S[t + s] : 0);
        int b = S[1024 + t] + ((1024 + t + s < 2048) ? S[1024 + t + s] : 0);
        __syncthreads();
        S[t] = a;
        S[1024 + t] = b;
        __syncthreads();
    }
    int k3 = sK3;
    if (S[t] >= k3 && S[t + 1] < k3) sT = t;
    if (t == 0 && S[1024] >= k3) sT = 1024;
    __syncthreads();
    int T = sT, K = sK;

    // gather candidates (matches >= T); order arbitrary, rank-count fixes determinism
    for (int i = 0; i < 32; ++i) {
        int j = i * 1024 + t;                       // int4 index
        int4 m4 = ((const int4*)matches)[j];
        int rbase = j * 4;
        if (m4.x >= T) { int p = atomicAdd(&gcnt, 1); if (p < CAPL) keys[p] = ((unsigned long long)m4.x << 32) | (unsigned int)(~(rbase)); }
        if (m4.y >= T) { int p = atomicAdd(&gcnt, 1); if (p < CAPL) keys[p] = ((unsigned long long)m4.y << 32) | (unsigned int)(~(rbase + 1)); }
        if (m4.z >= T) { int p = atomicAdd(&gcnt, 1); if (p < CAPL) keys[p] = ((unsigned long long)m4.z << 32) | (unsigned int)(~(rbase + 2)); }
        if (m4.w >= T) { int p = atomicAdd(&gcnt, 1); if (p < CAPL) keys[p] = ((unsigned long long)m4.w << 32) | (unsigned int)(~(rbase + 3)); }
    }
    __syncthreads();
    int G = gcnt;

    // pathological-overflow fallback (never taken for this data; correctness insurance)
    if (G > CAPL) {
        if (t == 0) {
            int n = 0;
            for (int v = 0; v < VROWS && n < k3; ++v)
                if (matches[v] > T) keys[n++] = ((unsigned long long)matches[v] << 32) | (unsigned int)(~v);
            for (int v = 0; v < VROWS && n < k3; ++v)
                if (matches[v] == T) keys[n++] = ((unsigned long long)matches[v] << 32) | (unsigned int)(~v);
            gcnt = n;
        }
        __syncthreads();
        G = gcnt;
    }

    // rank-count selection of top-k3 (matches desc, index asc)
    for (int i = t; i < G; i += 1024) {
        unsigned long long ki = keys[i];
        int rank = 0;
        for (int j = 0; j < G; ++j) rank += (keys[j] > ki) ? 1 : 0;
        if (rank < k3) sel[rank] = (int)(~(unsigned int)ki);
    }
    __syncthreads();

    // refine: cosine similarity, 1 wave per candidate round-robin
    int wave = t >> 6, lane = t & 63;
    float qn = sQn;
    for (int i = wave; i < k3; i += 16) {
        int row = sel[i];
        const float4* Wr = (const float4*)(W + (size_t)row * DIM);
        float dot = 0.f, ss = 0.f;
        for (int j2 = 0; j2 < 4; ++j2) {
            float4 a = Wr[j2 * 64 + lane];
            float4 b = ((const float4*)qs)[j2 * 64 + lane];
            dot += a.x * b.x + a.y * b.y + a.z * b.z + a.w * b.w;
            ss  += a.x * a.x + a.y * a.y + a.z * a.z + a.w * a.w;
        }
        for (int s = 1; s < 64; s <<= 1) {
            dot += __shfl_xor(dot, s);
            ss  += __shfl_xor(ss, s);
        }
        if (lane == 0) refined[i] = dot / ((sqrtf(ss) + 1e-12f) * qn);
    }
    __syncthreads();

    // final top-K by rank-count (value desc, candidate-position asc)
    if (t < k3) {
        float rv = refined[t];
        int rank = 0;
        for (int j = 0; j < k3; ++j)
            rank += ((refined[j] > rv) || (refined[j] == rv && j < t)) ? 1 : 0;
        if (rank < K) {
            out[rank] = rv;
            out[K + rank] = (float)sel[t];
        }
    }
}

extern "C" void kernel_launch(void* const* d_in, const int* in_sizes, int n_in,
                              void* d_out, int out_size, void* d_ws, size_t ws_size,
                              hipStream_t stream) {
    const float* q = (const float*)d_in[0];
    const float* W = (const float*)d_in[1];
    const int* topk = (const int*)d_in[2];
    float* out = (float*)d_out;
    char* ws = (char*)d_ws;

    signed char* ts = (signed char*)(ws + TS_OFF);
    int* matches = (int*)(ws + MATCH_OFF);
    int* partials = (int*)(ws + PART_OFF);

    kA_prep<<<1, 256, 0, stream>>>(q, ts);
    kB_coarse<<<KB_BLOCKS, 256, 0, stream>>>(W, (const int*)ts, matches);
    kHist<<<NHB, 1024, 0, stream>>>(matches, partials);
    kC_refine<<<1, 1024, 0, stream>>>(W, q, topk, matches, partials, out);
}

// Round 6
// 140.611 us; speedup vs baseline: 4.1380x; 1.0487x over previous
//
#include <hip/hip_runtime.h>
#include <stdint.h>

#define VROWS 131072
#define DIM   1024
#define TTHRESH 0.33f
#define TEPS    1e-10f
#define KB_BLOCKS 2048                 // 64 rows/block, 4 waves, 16 rows/wave
#define NHB   32                       // histogram / gather blocks
#define CAP   16384                    // global keys capacity
#define CAPL  4096                     // kF LDS staging capacity

// Exact rounding boundary: RN(x/d) > 0.33f  <=>  x >= MBOUND*d (d>0, exact in double).
// 0.33f has odd mantissa LSB; succ(0.33f) even => tie rounds up => inclusive >=.
#define MBOUND ((double)TTHRESH + 0x1p-26)

// ws layout (bytes):
//   ts       : int8[1024]        @ 0
//   gcount   : int               @ 1024
//   tval     : int               @ 1028
//   matches  : int32[VROWS]      @ 4096
//   partials : int[NHB*1025]     @ 4096 + 4*VROWS
//   keys     : uint64[CAP]       @ ... (8B aligned)
#define TS_OFF    0
#define GCOUNT_OFF 1024
#define TVAL_OFF  1028
#define MATCH_OFF 4096
#define PART_OFF  (MATCH_OFF + 4 * VROWS)
#define KEYS_OFF  ((PART_OFF + 4 * NHB * 1025 + 7) & ~7)

__device__ __forceinline__ int tern(float n) {
    return n > TTHRESH ? 1 : (n < -TTHRESH ? -1 : 0);
}

__device__ __forceinline__ float max4abs(float4 a) {
    return fmaxf(fmaxf(fabsf(a.x), fabsf(a.y)), fmaxf(fabsf(a.z), fabsf(a.w)));
}

// ---------------- kA: ternarize query + zero gcount ----------------
__global__ __launch_bounds__(256) void kA_prep(const float* __restrict__ q,
                                               signed char* __restrict__ ts,
                                               int* __restrict__ gcount) {
    __shared__ float red[256];
    int t = threadIdx.x;
    if (t == 0) *gcount = 0;
    float4 v = ((const float4*)q)[t];
    red[t] = max4abs(v);
    __syncthreads();
    for (int s = 128; s > 0; s >>= 1) {
        if (t < s) red[t] = fmaxf(red[t], red[t + s]);
        __syncthreads();
    }
    float denom = red[0] + TEPS;
    char4 c;
    c.x = (signed char)tern(v.x / denom);
    c.y = (signed char)tern(v.y / denom);
    c.z = (signed char)tern(v.z / denom);
    c.w = (signed char)tern(v.w / denom);
    ((char4*)ts)[t] = c;
}

// ---------------- kB: stream table, ballot+scalar-mask match count ----------------
// Per 64-elem slot j: bp=ballot(x>=r), bn=ballot(x<=-r), b0=~(bp|bn) (exact: |x|>=r <=> x>=r or -x>=r).
// matched = (bp&MP)|(bn&MN)|(b0&~(MP|MN)); count on the scalar pipe.
#define SLOT(x, j) { \
    unsigned long long bp = __ballot((x) >= r); \
    unsigned long long bn = __ballot((x) <= nr); \
    unsigned long long b0 = ~(bp | bn); \
    cnt += (int)__popcll((bp & MP[j]) | (bn & MN[j]) | (b0 & ~(MP[j] | MN[j]))); }

__global__ __launch_bounds__(256, 8) void kB_coarse(const float* __restrict__ W,
                                                    const int* __restrict__ ts_words,
                                                    int* __restrict__ matches) {
    __shared__ int tl[256];
    int t = threadIdx.x;
    tl[t] = ts_words[t];
    __syncthreads();
    int wave = t >> 6, lane = t & 63;
    unsigned long long MP[16], MN[16];   // wave-uniform -> SGPRs
#pragma unroll
    for (int j = 0; j < 4; ++j) {
        int w = tl[j * 64 + lane];
#pragma unroll
        for (int b = 0; b < 4; ++b) {
            int qv = (int)(signed char)((w >> (8 * b)) & 0xFF);
            MP[j * 4 + b] = __ballot(qv == 1);
            MN[j * 4 + b] = __ballot(qv == -1);
        }
    }
    int row0 = blockIdx.x * 64 + wave * 16;
    const float4* p = (const float4*)(W + (size_t)row0 * DIM) + lane;
    float4 c0 = p[0], c1 = p[64], c2 = p[128], c3 = p[192];
    float4 n0 = c0, n1 = c1, n2 = c2, n3 = c3;
#pragma unroll 1
    for (int i = 0; i < 16; ++i) {
        if (i < 15) {   // straight-line prefetch of next row (no wrap re-read)
            const float4* pn = (const float4*)(W + (size_t)(row0 + i + 1) * DIM) + lane;
            n0 = pn[0]; n1 = pn[64]; n2 = pn[128]; n3 = pn[192];
        }
        float m = fmaxf(fmaxf(max4abs(c0), max4abs(c1)), fmaxf(max4abs(c2), max4abs(c3)));
        for (int s = 1; s < 64; s <<= 1) m = fmaxf(m, __shfl_xor(m, s));
        float d = m + TEPS;                       // f32, as reference
        double md = MBOUND * (double)d;           // exact 49-bit product
        float r = (float)md;                      // smallest f32 >= md:
        if (!((double)r >= md)) r = __int_as_float(__float_as_int(r) + 1);
        float nr = -r;
        int cnt = 0;
        SLOT(c0.x, 0)  SLOT(c0.y, 1)  SLOT(c0.z, 2)  SLOT(c0.w, 3)
        SLOT(c1.x, 4)  SLOT(c1.y, 5)  SLOT(c1.z, 6)  SLOT(c1.w, 7)
        SLOT(c2.x, 8)  SLOT(c2.y, 9)  SLOT(c2.z, 10) SLOT(c2.w, 11)
        SLOT(c3.x, 12) SLOT(c3.y, 13) SLOT(c3.z, 14) SLOT(c3.w, 15)
        if (lane == 0) matches[row0 + i] = cnt;
        c0 = n0; c1 = n1; c2 = n2; c3 = n3;
    }
}

// ---------------- kHist: per-block LDS histogram -> partials ----------------
__global__ __launch_bounds__(1024) void kHist(const int* __restrict__ matches,
                                              int* __restrict__ partials) {
    __shared__ int h[1025];
    int t = threadIdx.x;
    if (t == 0) h[1024] = 0;
    h[t] = 0;
    __syncthreads();
    int gid = blockIdx.x * 1024 + t;            // NHB*1024 threads, 1 int4 (4 rows) each
    int4 m4 = ((const int4*)matches)[gid];
    atomicAdd(&h[m4.x], 1);
    atomicAdd(&h[m4.y], 1);
    atomicAdd(&h[m4.z], 1);
    atomicAdd(&h[m4.w], 1);
    __syncthreads();
    int* dst = partials + blockIdx.x * 1025;
    dst[t] = h[t];
    if (t == 0) dst[1024] = h[1024];
}

// ---------------- kGather: (redundant) T computation + parallel compaction ----------------
__global__ __launch_bounds__(1024) void kGather(const int* __restrict__ matches,
                                                const int* __restrict__ partials,
                                                const int* __restrict__ topk,
                                                unsigned long long* __restrict__ keys,
                                                int* __restrict__ gcount,
                                                int* __restrict__ tval) {
    __shared__ int S[2048];
    __shared__ int sT;
    int t = threadIdx.x;

    int K = *topk;
    if (K < 1) K = 1;
    if (K > 64) K = 64;
    int k3 = 3 * K;
    if (k3 > VROWS) k3 = VROWS;

    // merge NHB partial histograms (coalesced across t)
    int hb = 0, hb1 = 0;
    for (int k = 0; k < NHB; ++k) {
        hb += partials[k * 1025 + t];
        if (t == 0) hb1 += partials[k * 1025 + 1024];
    }
    S[t] = hb;
    S[1024 + t] = (t == 0) ? hb1 : 0;
    __syncthreads();

    // parallel suffix sum over S[0..2047]
    for (int s = 1; s < 2048; s <<= 1) {
        int a = S[t] + ((t + s < 2048) ? S[t + s] : 0);
        int b = S[1024 + t] + ((1024 + t + s < 2048) ? S[1024 + t + s] : 0);
        __syncthreads();
        S[t] = a;
        S[1024 + t] = b;
        __syncthreads();
    }
    if (S[t] >= k3 && S[t + 1] < k3) sT = t;
    if (t == 0 && S[1024] >= k3) sT = 1024;
    __syncthreads();
    int T = sT;
    if (t == 0) *tval = T;   // same value from all blocks

    // compact this block's slice (rows >= T); order arbitrary, rank-count later
    int j = blockIdx.x * 1024 + t;                 // int4 index
    int4 m4 = ((const int4*)matches)[j];
    int rbase = j * 4;
    if (m4.x >= T) { int p = atomicAdd(gcount, 1); if (p < CAP) keys[p] = ((unsigned long long)m4.x << 32) | (unsigned int)(~(rbase)); }
    if (m4.y >= T) { int p = atomicAdd(gcount, 1); if (p < CAP) keys[p] = ((unsigned long long)m4.y << 32) | (unsigned int)(~(rbase + 1)); }
    if (m4.z >= T) { int p = atomicAdd(gcount, 1); if (p < CAP) keys[p] = ((unsigned long long)m4.z << 32) | (unsigned int)(~(rbase + 2)); }
    if (m4.w >= T) { int p = atomicAdd(gcount, 1); if (p < CAP) keys[p] = ((unsigned long long)m4.w << 32) | (unsigned int)(~(rbase + 3)); }
}

// ---------------- kF: qnorm, rank-select, refine, output ----------------
__global__ __launch_bounds__(1024) void kF_final(const float* __restrict__ W,
                                                 const float* __restrict__ q,
                                                 const int* __restrict__ topk,
                                                 const int* __restrict__ matches,
                                                 const unsigned long long* __restrict__ keys,
                                                 const int* __restrict__ gcount,
                                                 const int* __restrict__ tval,
                                                 float* __restrict__ out) {
    __shared__ __align__(16) float qs[DIM];
    __shared__ float redf[1024];
    __shared__ unsigned long long kl[CAPL];
    __shared__ int sel[192];
    __shared__ float refined[192];
    __shared__ float sQn;
    __shared__ int sG;
    int t = threadIdx.x;

    if (t < 256) ((float4*)qs)[t] = ((const float4*)q)[t];
    __syncthreads();

    // query norm
    float qv = qs[t];
    redf[t] = qv * qv;
    __syncthreads();
    for (int s = 512; s > 0; s >>= 1) {
        if (t < s) redf[t] += redf[t + s];
        __syncthreads();
    }
    if (t == 0) sQn = sqrtf(redf[0]) + 1e-12f;

    int K = *topk;
    if (K < 1) K = 1;
    if (K > 64) K = 64;
    int k3 = 3 * K;
    if (k3 > VROWS) k3 = VROWS;

    int G = *gcount;
    if (G <= CAPL) {
        if (t < G) kl[t] = keys[t];          // G ~ 60 in practice
        if (t == 0) sG = G;
    } else {
        // pathological fallback (never taken for this data): serial rebuild
        if (t == 0) {
            int T = *tval;
            int n = 0;
            for (int v = 0; v < VROWS && n < k3; ++v)
                if (matches[v] > T) kl[n++] = ((unsigned long long)matches[v] << 32) | (unsigned int)(~v);
            for (int v = 0; v < VROWS && n < k3; ++v)
                if (matches[v] == T) kl[n++] = ((unsigned long long)matches[v] << 32) | (unsigned int)(~v);
            sG = n;
        }
    }
    __syncthreads();
    G = sG;

    // rank-count selection of top-k3 (matches desc, index asc)
    for (int i = t; i < G; i += 1024) {
        unsigned long long ki = kl[i];
        int rank = 0;
        for (int j = 0; j < G; ++j) rank += (kl[j] > ki) ? 1 : 0;
        if (rank < k3) sel[rank] = (int)(~(unsigned int)ki);
    }
    __syncthreads();

    // refine: cosine similarity, 1 wave per candidate round-robin
    int wave = t >> 6, lane = t & 63;
    float qn = sQn;
    for (int i = wave; i < k3; i += 16) {
        int row = sel[i];
        const float4* Wr = (const float4*)(W + (size_t)row * DIM);
        float dot = 0.f, ss = 0.f;
        for (int j2 = 0; j2 < 4; ++j2) {
            float4 a = Wr[j2 * 64 + lane];
            float4 b = ((const float4*)qs)[j2 * 64 + lane];
            dot += a.x * b.x + a.y * b.y + a.z * b.z + a.w * b.w;
            ss  += a.x * a.x + a.y * a.y + a.z * a.z + a.w * a.w;
        }
        for (int s = 1; s < 64; s <<= 1) {
            dot += __shfl_xor(dot, s);
            ss  += __shfl_xor(ss, s);
        }
        if (lane == 0) refined[i] = dot / ((sqrtf(ss) + 1e-12f) * qn);
    }
    __syncthreads();

    // final top-K by rank-count (value desc, candidate-position asc)
    if (t < k3) {
        float rv = refined[t];
        int rank = 0;
        for (int j = 0; j < k3; ++j)
            rank += ((refined[j] > rv) || (refined[j] == rv && j < t)) ? 1 : 0;
        if (rank < K) {
            out[rank] = rv;
            out[K + rank] = (float)sel[t];
        }
    }
}

extern "C" void kernel_launch(void* const* d_in, const int* in_sizes, int n_in,
                              void* d_out, int out_size, void* d_ws, size_t ws_size,
                              hipStream_t stream) {
    const float* q = (const float*)d_in[0];
    const float* W = (const float*)d_in[1];
    const int* topk = (const int*)d_in[2];
    float* out = (float*)d_out;
    char* ws = (char*)d_ws;

    signed char* ts = (signed char*)(ws + TS_OFF);
    int* gcount = (int*)(ws + GCOUNT_OFF);
    int* tval = (int*)(ws + TVAL_OFF);
    int* matches = (int*)(ws + MATCH_OFF);
    int* partials = (int*)(ws + PART_OFF);
    unsigned long long* keys = (unsigned long long*)(ws + KEYS_OFF);

    kA_prep<<<1, 256, 0, stream>>>(q, ts, gcount);
    kB_coarse<<<KB_BLOCKS, 256, 0, stream>>>(W, (const int*)ts, matches);
    kHist<<<NHB, 1024, 0, stream>>>(matches, partials);
    kGather<<<NHB, 1024, 0, stream>>>(matches, partials, topk, keys, gcount, tval);
    kF_final<<<1, 1024, 0, stream>>>(W, q, topk, matches, keys, gcount, tval, out);
}

// Round 7
// 117.623 us; speedup vs baseline: 4.9467x; 1.1954x over previous
//
#include <hip/hip_runtime.h>
#include <stdint.h>

#define VROWS 131072
#define DIM   1024
#define TTHRESH 0.33f
#define TEPS    1e-10f
#define KB_BLOCKS 2048                 // 64 rows/block, 4 waves, 16 rows/wave
#define NHB   32                       // histogram / gather blocks
#define CAP   16384                    // global keys capacity
#define CAPL  4096                     // kF LDS staging capacity

// Exact rounding boundary: RN(x/d) > 0.33f  <=>  x >= MBOUND*d (d>0, exact in double).
// 0.33f has odd mantissa LSB; succ(0.33f) even => tie rounds up => inclusive >=.
#define MBOUND ((double)TTHRESH + 0x1p-26)

// ws layout (bytes):
//   gcount   : int               @ 1024
//   tval     : int               @ 1028
//   matches  : int32[VROWS]      @ 4096
//   partials : int[NHB*1025]     @ 4096 + 4*VROWS
//   keys     : uint64[CAP]       @ ... (8B aligned)
#define GCOUNT_OFF 1024
#define TVAL_OFF  1028
#define MATCH_OFF 4096
#define PART_OFF  (MATCH_OFF + 4 * VROWS)
#define KEYS_OFF  ((PART_OFF + 4 * NHB * 1025 + 7) & ~7)

typedef float f32x4 __attribute__((ext_vector_type(4)));

__device__ __forceinline__ float max4abs(f32x4 a) {
    return fmaxf(fmaxf(fabsf(a.x), fabsf(a.y)), fmaxf(fabsf(a.z), fabsf(a.w)));
}

// smallest f32 >= MBOUND*(double)d
__device__ __forceinline__ float boundary(float d) {
    double md = MBOUND * (double)d;           // exact 49-bit product
    float r = (float)md;
    if (!((double)r >= md)) r = __int_as_float(__float_as_int(r) + 1);
    return r;
}

// ---------------- kB: stream table, ballot+scalar-mask match count ----------------
// Per 64-elem slot j: bp=ballot(x>=r), bn=ballot(x<=-r), b0=~(bp|bn) (exact: |x|>=r <=> x>=r or -x>=r).
#define SLOT(x, j) { \
    unsigned long long bp = __ballot((x) >= r); \
    unsigned long long bn = __ballot((x) <= nr); \
    unsigned long long b0 = ~(bp | bn); \
    cnt += (int)__popcll((bp & MP[j]) | (bn & MN[j]) | (b0 & ~(MP[j] | MN[j]))); }

__global__ __launch_bounds__(256, 8) void kB_coarse(const float* __restrict__ W,
                                                    const float* __restrict__ q,
                                                    int* __restrict__ matches) {
    int t = threadIdx.x;
    int wave = t >> 6, lane = t & 63;

    // --- self-compute ternary-query masks from q (replaces kA; exact boundary math) ---
    const f32x4* q4 = (const f32x4*)q;
    f32x4 qv0 = q4[lane], qv1 = q4[64 + lane], qv2 = q4[128 + lane], qv3 = q4[192 + lane];
    float mq = fmaxf(fmaxf(max4abs(qv0), max4abs(qv1)), fmaxf(max4abs(qv2), max4abs(qv3)));
    for (int s = 1; s < 64; s <<= 1) mq = fmaxf(mq, __shfl_xor(mq, s));
    float rq = boundary(mq + TEPS), nrq = -rq;
    unsigned long long MP[16], MN[16];   // wave-uniform -> SGPRs
#pragma unroll
    for (int j = 0; j < 4; ++j) {
        f32x4 v = (j == 0) ? qv0 : (j == 1) ? qv1 : (j == 2) ? qv2 : qv3;
        MP[j * 4 + 0] = __ballot(v.x >= rq);  MN[j * 4 + 0] = __ballot(v.x <= nrq);
        MP[j * 4 + 1] = __ballot(v.y >= rq);  MN[j * 4 + 1] = __ballot(v.y <= nrq);
        MP[j * 4 + 2] = __ballot(v.z >= rq);  MN[j * 4 + 2] = __ballot(v.z <= nrq);
        MP[j * 4 + 3] = __ballot(v.w >= rq);  MN[j * 4 + 3] = __ballot(v.w <= nrq);
    }

    // --- stream 16 rows, nontemporal (single-touch stream; don't churn L3) ---
    int row0 = blockIdx.x * 64 + wave * 16;
    const f32x4* p = (const f32x4*)(W + (size_t)row0 * DIM) + lane;
    f32x4 c0 = __builtin_nontemporal_load(p);
    f32x4 c1 = __builtin_nontemporal_load(p + 64);
    f32x4 c2 = __builtin_nontemporal_load(p + 128);
    f32x4 c3 = __builtin_nontemporal_load(p + 192);
    f32x4 n0 = c0, n1 = c1, n2 = c2, n3 = c3;
#pragma unroll 1
    for (int i = 0; i < 16; ++i) {
        if (i < 15) {   // straight-line prefetch of next row
            const f32x4* pn = (const f32x4*)(W + (size_t)(row0 + i + 1) * DIM) + lane;
            n0 = __builtin_nontemporal_load(pn);
            n1 = __builtin_nontemporal_load(pn + 64);
            n2 = __builtin_nontemporal_load(pn + 128);
            n3 = __builtin_nontemporal_load(pn + 192);
        }
        float m = fmaxf(fmaxf(max4abs(c0), max4abs(c1)), fmaxf(max4abs(c2), max4abs(c3)));
        for (int s = 1; s < 64; s <<= 1) m = fmaxf(m, __shfl_xor(m, s));
        float r = boundary(m + TEPS), nr = -r;
        int cnt = 0;
        SLOT(c0.x, 0)  SLOT(c0.y, 1)  SLOT(c0.z, 2)  SLOT(c0.w, 3)
        SLOT(c1.x, 4)  SLOT(c1.y, 5)  SLOT(c1.z, 6)  SLOT(c1.w, 7)
        SLOT(c2.x, 8)  SLOT(c2.y, 9)  SLOT(c2.z, 10) SLOT(c2.w, 11)
        SLOT(c3.x, 12) SLOT(c3.y, 13) SLOT(c3.z, 14) SLOT(c3.w, 15)
        if (lane == 0) matches[row0 + i] = cnt;
        c0 = n0; c1 = n1; c2 = n2; c3 = n3;
    }
}

// ---------------- kHist: per-block LDS histogram -> partials; zero gcount ----------------
__global__ __launch_bounds__(1024) void kHist(const int* __restrict__ matches,
                                              int* __restrict__ partials,
                                              int* __restrict__ gcount) {
    __shared__ int h[1025];
    int t = threadIdx.x;
    if (t == 0) h[1024] = 0;
    if (blockIdx.x == 0 && t == 0) *gcount = 0;
    h[t] = 0;
    __syncthreads();
    int gid = blockIdx.x * 1024 + t;            // NHB*1024 threads, 1 int4 (4 rows) each
    int4 m4 = ((const int4*)matches)[gid];
    atomicAdd(&h[m4.x], 1);
    atomicAdd(&h[m4.y], 1);
    atomicAdd(&h[m4.z], 1);
    atomicAdd(&h[m4.w], 1);
    __syncthreads();
    int* dst = partials + blockIdx.x * 1025;
    dst[t] = h[t];
    if (t == 0) dst[1024] = h[1024];
}

// ---------------- kGather: (redundant) T computation + parallel compaction ----------------
__global__ __launch_bounds__(1024) void kGather(const int* __restrict__ matches,
                                                const int* __restrict__ partials,
                                                const int* __restrict__ topk,
                                                unsigned long long* __restrict__ keys,
                                                int* __restrict__ gcount,
                                                int* __restrict__ tval) {
    __shared__ int S[2048];
    __shared__ int sT;
    int t = threadIdx.x;

    int K = *topk;
    if (K < 1) K = 1;
    if (K > 64) K = 64;
    int k3 = 3 * K;
    if (k3 > VROWS) k3 = VROWS;

    // merge NHB partial histograms (coalesced across t)
    int hb = 0, hb1 = 0;
    for (int k = 0; k < NHB; ++k) {
        hb += partials[k * 1025 + t];
        if (t == 0) hb1 += partials[k * 1025 + 1024];
    }
    S[t] = hb;
    S[1024 + t] = (t == 0) ? hb1 : 0;
    __syncthreads();

    // parallel suffix sum over S[0..2047]
    for (int s = 1; s < 2048; s <<= 1) {
        int a = S[t] + ((t + s < 2048) ? S[t + s] : 0);
        int b = S[1024 + t] + ((1024 + t + s < 2048) ? S[1024 + t + s] : 0);
        __syncthreads();
        S[t] = a;
        S[1024 + t] = b;
        __syncthreads();
    }
    if (S[t] >= k3 && S[t + 1] < k3) sT = t;
    if (t == 0 && S[1024] >= k3) sT = 1024;
    __syncthreads();
    int T = sT;
    if (t == 0) *tval = T;   // same value from all blocks

    // compact this block's slice (rows >= T); order arbitrary, rank-count later
    int j = blockIdx.x * 1024 + t;                 // int4 index
    int4 m4 = ((const int4*)matches)[j];
    int rbase = j * 4;
    if (m4.x >= T) { int p = atomicAdd(gcount, 1); if (p < CAP) keys[p] = ((unsigned long long)m4.x << 32) | (unsigned int)(~(rbase)); }
    if (m4.y >= T) { int p = atomicAdd(gcount, 1); if (p < CAP) keys[p] = ((unsigned long long)m4.y << 32) | (unsigned int)(~(rbase + 1)); }
    if (m4.z >= T) { int p = atomicAdd(gcount, 1); if (p < CAP) keys[p] = ((unsigned long long)m4.z << 32) | (unsigned int)(~(rbase + 2)); }
    if (m4.w >= T) { int p = atomicAdd(gcount, 1); if (p < CAP) keys[p] = ((unsigned long long)m4.w << 32) | (unsigned int)(~(rbase + 3)); }
}

// ---------------- kF: qnorm, rank-select, refine, output ----------------
__global__ __launch_bounds__(1024) void kF_final(const float* __restrict__ W,
                                                 const float* __restrict__ q,
                                                 const int* __restrict__ topk,
                                                 const int* __restrict__ matches,
                                                 const unsigned long long* __restrict__ keys,
                                                 const int* __restrict__ gcount,
                                                 const int* __restrict__ tval,
                                                 float* __restrict__ out) {
    __shared__ __align__(16) float qs[DIM];
    __shared__ float redf[1024];
    __shared__ unsigned long long kl[CAPL];
    __shared__ int sel[192];
    __shared__ float refined[192];
    __shared__ float sQn;
    __shared__ int sG;
    int t = threadIdx.x;

    if (t < 256) ((float4*)qs)[t] = ((const float4*)q)[t];
    __syncthreads();

    // query norm
    float qv = qs[t];
    redf[t] = qv * qv;
    __syncthreads();
    for (int s = 512; s > 0; s >>= 1) {
        if (t < s) redf[t] += redf[t + s];
        __syncthreads();
    }
    if (t == 0) sQn = sqrtf(redf[0]) + 1e-12f;

    int K = *topk;
    if (K < 1) K = 1;
    if (K > 64) K = 64;
    int k3 = 3 * K;
    if (k3 > VROWS) k3 = VROWS;

    int G = *gcount;
    if (G <= CAPL) {
        if (t < G) kl[t] = keys[t];          // G ~ 60 in practice
        if (t == 0) sG = G;
    } else {
        // pathological fallback (never taken for this data): serial rebuild
        if (t == 0) {
            int T = *tval;
            int n = 0;
            for (int v = 0; v < VROWS && n < k3; ++v)
                if (matches[v] > T) kl[n++] = ((unsigned long long)matches[v] << 32) | (unsigned int)(~v);
            for (int v = 0; v < VROWS && n < k3; ++v)
                if (matches[v] == T) kl[n++] = ((unsigned long long)matches[v] << 32) | (unsigned int)(~v);
            sG = n;
        }
    }
    __syncthreads();
    G = sG;

    // rank-count selection of top-k3 (matches desc, index asc)
    for (int i = t; i < G; i += 1024) {
        unsigned long long ki = kl[i];
        int rank = 0;
        for (int j = 0; j < G; ++j) rank += (kl[j] > ki) ? 1 : 0;
        if (rank < k3) sel[rank] = (int)(~(unsigned int)ki);
    }
    __syncthreads();

    // refine: cosine similarity, 1 wave per candidate round-robin
    int wave = t >> 6, lane = t & 63;
    float qn = sQn;
    for (int i = wave; i < k3; i += 16) {
        int row = sel[i];
        const float4* Wr = (const float4*)(W + (size_t)row * DIM);
        float dot = 0.f, ss = 0.f;
        for (int j2 = 0; j2 < 4; ++j2) {
            float4 a = Wr[j2 * 64 + lane];
            float4 b = ((const float4*)qs)[j2 * 64 + lane];
            dot += a.x * b.x + a.y * b.y + a.z * b.z + a.w * b.w;
            ss  += a.x * a.x + a.y * a.y + a.z * a.z + a.w * a.w;
        }
        for (int s = 1; s < 64; s <<= 1) {
            dot += __shfl_xor(dot, s);
            ss  += __shfl_xor(ss, s);
        }
        if (lane == 0) refined[i] = dot / ((sqrtf(ss) + 1e-12f) * qn);
    }
    __syncthreads();

    // final top-K by rank-count (value desc, candidate-position asc)
    if (t < k3) {
        float rv = refined[t];
        int rank = 0;
        for (int j = 0; j < k3; ++j)
            rank += ((refined[j] > rv) || (refined[j] == rv && j < t)) ? 1 : 0;
        if (rank < K) {
            out[rank] = rv;
            out[K + rank] = (float)sel[t];
        }
    }
}

extern "C" void kernel_launch(void* const* d_in, const int* in_sizes, int n_in,
                              void* d_out, int out_size, void* d_ws, size_t ws_size,
                              hipStream_t stream) {
    const float* q = (const float*)d_in[0];
    const float* W = (const float*)d_in[1];
    const int* topk = (const int*)d_in[2];
    float* out = (float*)d_out;
    char* ws = (char*)d_ws;

    int* gcount = (int*)(ws + GCOUNT_OFF);
    int* tval = (int*)(ws + TVAL_OFF);
    int* matches = (int*)(ws + MATCH_OFF);
    int* partials = (int*)(ws + PART_OFF);
    unsigned long long* keys = (unsigned long long*)(ws + KEYS_OFF);

    kB_coarse<<<KB_BLOCKS, 256, 0, stream>>>(W, q, matches);
    kHist<<<NHB, 1024, 0, stream>>>(matches, partials, gcount);
    kGather<<<NHB, 1024, 0, stream>>>(matches, partials, topk, keys, gcount, tval);
    kF_final<<<1, 1024, 0, stream>>>(W, q, topk, matches, keys, gcount, tval, out);
}

// Round 8
// 108.346 us; speedup vs baseline: 5.3703x; 1.0856x over previous
//
#include <hip/hip_runtime.h>
#include <stdint.h>

#define VROWS 131072
#define DIM   1024
#define TTHRESH 0.33f
#define TEPS    1e-10f
#define KB_BLOCKS 2048                 // 64 rows/block, 4 waves, 16 rows/wave
#define REG_BLOCKS 832                 // blocks 0..831 -> rows [0, 53248): 208 MiB L3-resident (temporal loads)
#define NHB   32                       // histogram / gather blocks
#define CAP   16384                    // global keys capacity
#define CAPL  4096                     // kF LDS staging capacity

// Exact rounding boundary: RN(x/d) > 0.33f  <=>  x >= MBOUND*d (d>0, exact in double).
// 0.33f has odd mantissa LSB; succ(0.33f) even => tie rounds up => inclusive >=.
#define MBOUND ((double)TTHRESH + 0x1p-26)

// ws layout (bytes):
//   gcount   : int               @ 1024
//   tval     : int               @ 1028
//   matches  : int32[VROWS]      @ 4096
//   partials : int[NHB*1025]     @ 4096 + 4*VROWS
//   keys     : uint64[CAP]       @ ... (8B aligned)
#define GCOUNT_OFF 1024
#define TVAL_OFF  1028
#define MATCH_OFF 4096
#define PART_OFF  (MATCH_OFF + 4 * VROWS)
#define KEYS_OFF  ((PART_OFF + 4 * NHB * 1025 + 7) & ~7)

typedef float f32x4 __attribute__((ext_vector_type(4)));

__device__ __forceinline__ float max4abs(f32x4 a) {
    return fmaxf(fmaxf(fabsf(a.x), fabsf(a.y)), fmaxf(fabsf(a.z), fabsf(a.w)));
}

// smallest f32 >= MBOUND*(double)d
__device__ __forceinline__ float boundary(float d) {
    double md = MBOUND * (double)d;           // exact 49-bit product
    float r = (float)md;
    if (!((double)r >= md)) r = __int_as_float(__float_as_int(r) + 1);
    return r;
}

// ---------------- kB: stream table, ballot+scalar-mask match count ----------------
// Per 64-elem slot j: bp=ballot(x>=r), bn=ballot(x<=-r), b0=~(bp|bn) (exact: |x|>=r <=> x>=r or -x>=r).
#define SLOT(x, j) { \
    unsigned long long bp = __ballot((x) >= r); \
    unsigned long long bn = __ballot((x) <= nr); \
    unsigned long long b0 = ~(bp | bn); \
    cnt += (int)__popcll((bp & MP[j]) | (bn & MN[j]) | (b0 & ~(MP[j] | MN[j]))); }

template <bool NT>
__device__ __forceinline__ f32x4 ldW(const f32x4* p) {
    if (NT) return __builtin_nontemporal_load(p);
    return *p;
}

template <bool NT>
__device__ __forceinline__ void rows16(const float* __restrict__ W, int row0, int lane,
                                       const unsigned long long* MP, const unsigned long long* MN,
                                       int* __restrict__ matches) {
    const f32x4* p = (const f32x4*)(W + (size_t)row0 * DIM) + lane;
    f32x4 c0 = ldW<NT>(p), c1 = ldW<NT>(p + 64), c2 = ldW<NT>(p + 128), c3 = ldW<NT>(p + 192);
    f32x4 n0 = c0, n1 = c1, n2 = c2, n3 = c3;
#pragma unroll 1
    for (int i = 0; i < 16; ++i) {
        if (i < 15) {   // straight-line prefetch of next row
            const f32x4* pn = (const f32x4*)(W + (size_t)(row0 + i + 1) * DIM) + lane;
            n0 = ldW<NT>(pn); n1 = ldW<NT>(pn + 64); n2 = ldW<NT>(pn + 128); n3 = ldW<NT>(pn + 192);
        }
        float m = fmaxf(fmaxf(max4abs(c0), max4abs(c1)), fmaxf(max4abs(c2), max4abs(c3)));
        for (int s = 1; s < 64; s <<= 1) m = fmaxf(m, __shfl_xor(m, s));
        float r = boundary(m + TEPS), nr = -r;
        int cnt = 0;
        SLOT(c0.x, 0)  SLOT(c0.y, 1)  SLOT(c0.z, 2)  SLOT(c0.w, 3)
        SLOT(c1.x, 4)  SLOT(c1.y, 5)  SLOT(c1.z, 6)  SLOT(c1.w, 7)
        SLOT(c2.x, 8)  SLOT(c2.y, 9)  SLOT(c2.z, 10) SLOT(c2.w, 11)
        SLOT(c3.x, 12) SLOT(c3.y, 13) SLOT(c3.z, 14) SLOT(c3.w, 15)
        if (lane == 0) matches[row0 + i] = cnt;
        c0 = n0; c1 = n1; c2 = n2; c3 = n3;
    }
}

__global__ __launch_bounds__(256, 8) void kB_coarse(const float* __restrict__ W,
                                                    const float* __restrict__ q,
                                                    int* __restrict__ matches) {
    int t = threadIdx.x;
    int wave = t >> 6, lane = t & 63;

    // --- self-compute ternary-query masks from q (exact boundary math) ---
    const f32x4* q4 = (const f32x4*)q;
    f32x4 qv0 = q4[lane], qv1 = q4[64 + lane], qv2 = q4[128 + lane], qv3 = q4[192 + lane];
    float mq = fmaxf(fmaxf(max4abs(qv0), max4abs(qv1)), fmaxf(max4abs(qv2), max4abs(qv3)));
    for (int s = 1; s < 64; s <<= 1) mq = fmaxf(mq, __shfl_xor(mq, s));
    float rq = boundary(mq + TEPS), nrq = -rq;
    unsigned long long MP[16], MN[16];   // wave-uniform -> SGPRs
#pragma unroll
    for (int j = 0; j < 4; ++j) {
        f32x4 v = (j == 0) ? qv0 : (j == 1) ? qv1 : (j == 2) ? qv2 : qv3;
        MP[j * 4 + 0] = __ballot(v.x >= rq);  MN[j * 4 + 0] = __ballot(v.x <= nrq);
        MP[j * 4 + 1] = __ballot(v.y >= rq);  MN[j * 4 + 1] = __ballot(v.y <= nrq);
        MP[j * 4 + 2] = __ballot(v.z >= rq);  MN[j * 4 + 2] = __ballot(v.z <= nrq);
        MP[j * 4 + 3] = __ballot(v.w >= rq);  MN[j * 4 + 3] = __ballot(v.w <= nrq);
    }

    // --- hybrid: scrambled block->region map so L3 and HBM streams run concurrently ---
    int bb = (blockIdx.x * 997) & (KB_BLOCKS - 1);   // odd multiplier: bijection mod 2048
    int row0 = bb * 64 + wave * 16;
    if (bb < REG_BLOCKS) {
        rows16<false>(W, row0, lane, MP, MN, matches);   // temporal: stays L3-resident across replays
    } else {
        rows16<true>(W, row0, lane, MP, MN, matches);    // nt: HBM stream, no L3 churn
    }
}

// ---------------- kHist: per-block LDS histogram -> partials; zero gcount ----------------
__global__ __launch_bounds__(1024) void kHist(const int* __restrict__ matches,
                                              int* __restrict__ partials,
                                              int* __restrict__ gcount) {
    __shared__ int h[1025];
    int t = threadIdx.x;
    if (t == 0) h[1024] = 0;
    if (blockIdx.x == 0 && t == 0) *gcount = 0;
    h[t] = 0;
    __syncthreads();
    int gid = blockIdx.x * 1024 + t;            // NHB*1024 threads, 1 int4 (4 rows) each
    int4 m4 = ((const int4*)matches)[gid];
    atomicAdd(&h[m4.x], 1);
    atomicAdd(&h[m4.y], 1);
    atomicAdd(&h[m4.z], 1);
    atomicAdd(&h[m4.w], 1);
    __syncthreads();
    int* dst = partials + blockIdx.x * 1025;
    dst[t] = h[t];
    if (t == 0) dst[1024] = h[1024];
}

// ---------------- kGather: (redundant) T computation + parallel compaction ----------------
__global__ __launch_bounds__(1024) void kGather(const int* __restrict__ matches,
                                                const int* __restrict__ partials,
                                                const int* __restrict__ topk,
                                                unsigned long long* __restrict__ keys,
                                                int* __restrict__ gcount,
                                                int* __restrict__ tval) {
    __shared__ int S[2048];
    __shared__ int sT;
    int t = threadIdx.x;

    int K = *topk;
    if (K < 1) K = 1;
    if (K > 64) K = 64;
    int k3 = 3 * K;
    if (k3 > VROWS) k3 = VROWS;

    // merge NHB partial histograms (coalesced across t)
    int hb = 0, hb1 = 0;
    for (int k = 0; k < NHB; ++k) {
        hb += partials[k * 1025 + t];
        if (t == 0) hb1 += partials[k * 1025 + 1024];
    }
    S[t] = hb;
    S[1024 + t] = (t == 0) ? hb1 : 0;
    __syncthreads();

    // parallel suffix sum over S[0..2047]
    for (int s = 1; s < 2048; s <<= 1) {
        int a = S[t] + ((t + s < 2048) ? S[t + s] : 0);
        int b = S[1024 + t] + ((1024 + t + s < 2048) ? S[1024 + t + s] : 0);
        __syncthreads();
        S[t] = a;
        S[1024 + t] = b;
        __syncthreads();
    }
    if (S[t] >= k3 && S[t + 1] < k3) sT = t;
    if (t == 0 && S[1024] >= k3) sT = 1024;
    __syncthreads();
    int T = sT;
    if (t == 0) *tval = T;   // same value from all blocks

    // compact this block's slice (rows >= T); order arbitrary, rank-count later
    int j = blockIdx.x * 1024 + t;                 // int4 index
    int4 m4 = ((const int4*)matches)[j];
    int rbase = j * 4;
    if (m4.x >= T) { int p = atomicAdd(gcount, 1); if (p < CAP) keys[p] = ((unsigned long long)m4.x << 32) | (unsigned int)(~(rbase)); }
    if (m4.y >= T) { int p = atomicAdd(gcount, 1); if (p < CAP) keys[p] = ((unsigned long long)m4.y << 32) | (unsigned int)(~(rbase + 1)); }
    if (m4.z >= T) { int p = atomicAdd(gcount, 1); if (p < CAP) keys[p] = ((unsigned long long)m4.z << 32) | (unsigned int)(~(rbase + 2)); }
    if (m4.w >= T) { int p = atomicAdd(gcount, 1); if (p < CAP) keys[p] = ((unsigned long long)m4.w << 32) | (unsigned int)(~(rbase + 3)); }
}

// ---------------- kF: qnorm, rank-select, refine, output ----------------
__global__ __launch_bounds__(1024) void kF_final(const float* __restrict__ W,
                                                 const float* __restrict__ q,
                                                 const int* __restrict__ topk,
                                                 const int* __restrict__ matches,
                                                 const unsigned long long* __restrict__ keys,
                                                 const int* __restrict__ gcount,
                                                 const int* __restrict__ tval,
                                                 float* __restrict__ out) {
    __shared__ __align__(16) float qs[DIM];
    __shared__ float redf[1024];
    __shared__ unsigned long long kl[CAPL];
    __shared__ int sel[192];
    __shared__ float refined[192];
    __shared__ float sQn;
    __shared__ int sG;
    int t = threadIdx.x;

    if (t < 256) ((float4*)qs)[t] = ((const float4*)q)[t];
    __syncthreads();

    // query norm
    float qv = qs[t];
    redf[t] = qv * qv;
    __syncthreads();
    for (int s = 512; s > 0; s >>= 1) {
        if (t < s) redf[t] += redf[t + s];
        __syncthreads();
    }
    if (t == 0) sQn = sqrtf(redf[0]) + 1e-12f;

    int K = *topk;
    if (K < 1) K = 1;
    if (K > 64) K = 64;
    int k3 = 3 * K;
    if (k3 > VROWS) k3 = VROWS;

    int G = *gcount;
    if (G <= CAPL) {
        if (t < G) kl[t] = keys[t];          // G ~ 60 in practice
        if (t == 0) sG = G;
    } else {
        // pathological fallback (never taken for this data): serial rebuild
        if (t == 0) {
            int T = *tval;
            int n = 0;
            for (int v = 0; v < VROWS && n < k3; ++v)
                if (matches[v] > T) kl[n++] = ((unsigned long long)matches[v] << 32) | (unsigned int)(~v);
            for (int v = 0; v < VROWS && n < k3; ++v)
                if (matches[v] == T) kl[n++] = ((unsigned long long)matches[v] << 32) | (unsigned int)(~v);
            sG = n;
        }
    }
    __syncthreads();
    G = sG;

    // rank-count selection of top-k3 (matches desc, index asc)
    for (int i = t; i < G; i += 1024) {
        unsigned long long ki = kl[i];
        int rank = 0;
        for (int j = 0; j < G; ++j) rank += (kl[j] > ki) ? 1 : 0;
        if (rank < k3) sel[rank] = (int)(~(unsigned int)ki);
    }
    __syncthreads();

    // refine: cosine similarity, 1 wave per candidate round-robin
    int wave = t >> 6, lane = t & 63;
    float qn = sQn;
    for (int i = wave; i < k3; i += 16) {
        int row = sel[i];
        const float4* Wr = (const float4*)(W + (size_t)row * DIM);
        float dot = 0.f, ss = 0.f;
        for (int j2 = 0; j2 < 4; ++j2) {
            float4 a = Wr[j2 * 64 + lane];
            float4 b = ((const float4*)qs)[j2 * 64 + lane];
            dot += a.x * b.x + a.y * b.y + a.z * b.z + a.w * b.w;
            ss  += a.x * a.x + a.y * a.y + a.z * a.z + a.w * a.w;
        }
        for (int s = 1; s < 64; s <<= 1) {
            dot += __shfl_xor(dot, s);
            ss  += __shfl_xor(ss, s);
        }
        if (lane == 0) refined[i] = dot / ((sqrtf(ss) + 1e-12f) * qn);
    }
    __syncthreads();

    // final top-K by rank-count (value desc, candidate-position asc)
    if (t < k3) {
        float rv = refined[t];
        int rank = 0;
        for (int j = 0; j < k3; ++j)
            rank += ((refined[j] > rv) || (refined[j] == rv && j < t)) ? 1 : 0;
        if (rank < K) {
            out[rank] = rv;
            out[K + rank] = (float)sel[t];
        }
    }
}

extern "C" void kernel_launch(void* const* d_in, const int* in_sizes, int n_in,
                              void* d_out, int out_size, void* d_ws, size_t ws_size,
                              hipStream_t stream) {
    const float* q = (const float*)d_in[0];
    const float* W = (const float*)d_in[1];
    const int* topk = (const int*)d_in[2];
    float* out = (float*)d_out;
    char* ws = (char*)d_ws;

    int* gcount = (int*)(ws + GCOUNT_OFF);
    int* tval = (int*)(ws + TVAL_OFF);
    int* matches = (int*)(ws + MATCH_OFF);
    int* partials = (int*)(ws + PART_OFF);
    unsigned long long* keys = (unsigned long long*)(ws + KEYS_OFF);

    kB_coarse<<<KB_BLOCKS, 256, 0, stream>>>(W, q, matches);
    kHist<<<NHB, 1024, 0, stream>>>(matches, partials, gcount);
    kGather<<<NHB, 1024, 0, stream>>>(matches, partials, topk, keys, gcount, tval);
    kF_final<<<1, 1024, 0, stream>>>(W, q, topk, matches, keys, gcount, tval, out);
}